// Round 11
// baseline (348.932 us; speedup 1.0000x reference)
//
#include <hip/hip_runtime.h>
#include <hip/hip_bf16.h>
#include <math.h>

// Problem constants
#define B_   128
#define H_   512
#define TZ   64
#define TU   128
#define V_   8000
#define VC   8064            // V + TZ
#define GIN  1541            // E + 2H + 5
#define GINP 1568            // GIN padded to multiple of 32
#define G3   1536            // 3*H
#define NB   8               // n-blocks per 512-wide energy GEMM

typedef float f32x4 __attribute__((ext_vector_type(4)));
typedef __bf16 bf16x8 __attribute__((ext_vector_type(8)));

__device__ __forceinline__ float sigmoidf_(float x){ return 1.f/(1.f+__expf(-x)); }

__device__ __forceinline__ bf16x8 load8_bf16(const float* __restrict__ p){
  float4 x = *(const float4*)p;
  float4 y = *(const float4*)(p+4);
  bf16x8 r;
  r[0]=(__bf16)x.x; r[1]=(__bf16)x.y; r[2]=(__bf16)x.z; r[3]=(__bf16)x.w;
  r[4]=(__bf16)y.x; r[5]=(__bf16)y.y; r[6]=(__bf16)y.z; r[7]=(__bf16)y.w;
  return r;
}
__device__ __forceinline__ void cvt8(const float* __restrict__ s, __bf16* __restrict__ d){
  *(bf16x8*)d = load8_bf16(s);
}

// ---------------------------------------------------------------------------
// One-pass fp32->bf16 conversion of all MFMA operands (unit = 8 elems),
// including gru_W_ih with row padding 1541 -> 1568 and proj_W (R8 config).
// ---------------------------------------------------------------------------
#define U_Z   524288u     // z_enc
#define U_U   1048576u    // u_enc
#define U_H   8192u       // hidden
#define U_ZW  65536u      // attn_z_W
#define U_UW  65536u      // attn_u_W
#define U_CW  32768u      // copy2_W
#define U_WHH 98304u      // gru_W_hh
#define U_PW  1536000u    // proj_W
#define U_WIH 301056u     // gru_W_ih padded: 1536*1568/8
#define CVT_UNITS (U_Z+U_U+U_H+U_ZW+U_UW+U_CW+U_WHH+U_PW+U_WIH)

__global__ __launch_bounds__(256) void cvt_all(
    const float* __restrict__ z, const float* __restrict__ u, const float* __restrict__ hid,
    const float* __restrict__ zW, const float* __restrict__ uW, const float* __restrict__ cW,
    const float* __restrict__ whh, const float* __restrict__ pW, const float* __restrict__ wih,
    __bf16* __restrict__ zb, __bf16* __restrict__ ub, __bf16* __restrict__ hb,
    __bf16* __restrict__ zWb, __bf16* __restrict__ uWb, __bf16* __restrict__ cWb,
    __bf16* __restrict__ whhb, __bf16* __restrict__ pWb, __bf16* __restrict__ Wp)
{
  unsigned t = blockIdx.x*256u + threadIdx.x;
  if (t >= CVT_UNITS) return;
  unsigned o = t;
  if (o >= CVT_UNITS - U_WIH) {           // gru_W_ih pad segment (scalar loads)
    o -= (CVT_UNITS - U_WIH);
    unsigned r = o / (GINP/8), cu = o % (GINP/8);
    int c0 = cu*8;
    const float* src = wih + (size_t)r*GIN;
    bf16x8 v;
#pragma unroll
    for (int e = 0; e < 8; ++e) {
      int c = c0 + e;
      v[e] = (__bf16)((c < GIN) ? src[c] : 0.f);
    }
    *(bf16x8*)(Wp + (size_t)r*GINP + c0) = v;
    return;
  }
  const float* s; __bf16* d;
  if      (o < U_Z)                   { s=z;   d=zb;   }
  else if ((o-=U_Z)   < U_U)          { s=u;   d=ub;   }
  else if ((o-=U_U)   < U_H)          { s=hid; d=hb;   }
  else if ((o-=U_H)   < U_ZW)         { s=zW;  d=zWb;  }
  else if ((o-=U_ZW)  < U_UW)         { s=uW;  d=uWb;  }
  else if ((o-=U_UW)  < U_CW)         { s=cW;  d=cWb;  }
  else if ((o-=U_CW)  < U_WHH)        { s=whh; d=whhb; }
  else     { o-=U_WHH;                  s=pW;  d=pWb;  }
  cvt8(s + (size_t)o*8, d + (size_t)o*8);
}

// ---------------------------------------------------------------------------
// Fused hidden-side GEMMs: hWz (16 tiles), hWu (16), gh (48). 80 tiles total.
// ---------------------------------------------------------------------------
__global__ __launch_bounds__(256) void hidden3(
    const __bf16* __restrict__ hb,
    const __bf16* __restrict__ zWb, const float* __restrict__ zbias, float* __restrict__ hWz,
    const __bf16* __restrict__ uWb, const float* __restrict__ ubias, float* __restrict__ hWu,
    const __bf16* __restrict__ whhb, const float* __restrict__ hbias, float* __restrict__ gh)
{
  const int wv = threadIdx.x >> 6, lane = threadIdx.x & 63;
  const int tile = blockIdx.x*4 + wv;
  if (tile >= 80) return;
  const __bf16* W; const float* bias; float* C; int ldw, ldc, nbn, lt;
  if (tile < 16)      { W=zWb;  bias=zbias; C=hWz; ldw=2*H_; ldc=H_; nbn=8;  lt=tile; }
  else if (tile < 32) { W=uWb;  bias=ubias; C=hWu; ldw=2*H_; ldc=H_; nbn=8;  lt=tile-16; }
  else                { W=whhb; bias=hbias; C=gh;  ldw=H_;   ldc=G3; nbn=24; lt=tile-32; }
  const int bn = (lt % nbn) * 64, bm = (lt / nbn) * 64;
  const int col = lane & 15, g = lane >> 4;
  f32x4 acc[4][4] = {};
  for (int k0 = 0; k0 < 512; k0 += 32) {
    const int k = k0 + g*8;
    bf16x8 af[4], bw[4];
#pragma unroll
    for (int i = 0; i < 4; ++i) {
      af[i] = *(const bf16x8*)(hb + (size_t)(bm + i*16 + col)*H_ + k);
      bw[i] = *(const bf16x8*)(W  + (size_t)(bn + i*16 + col)*ldw + k);
    }
#pragma unroll
    for (int i = 0; i < 4; ++i)
#pragma unroll
      for (int j = 0; j < 4; ++j)
        acc[i][j] = __builtin_amdgcn_mfma_f32_16x16x32_bf16(af[i], bw[j], acc[i][j], 0, 0, 0);
  }
#pragma unroll
  for (int mi = 0; mi < 4; ++mi)
#pragma unroll
    for (int r = 0; r < 4; ++r) {
      int m = bm + mi*16 + g*4 + r;
#pragma unroll
      for (int ni = 0; ni < 4; ++ni) {
        int n = bn + ni*16 + col;
        C[(size_t)m*ldc + n] = acc[mi][ni][r] + bias[n];
      }
    }
}

// ---------------------------------------------------------------------------
// Fused z+u attention energies, widened per-wave tile 128x64 (acc[8][4]):
// 12 fragment loads per 32 MFMA (was 8 per 16). NB=8 layout unchanged.
// z: 512 tiles (64 m-blocks x 8 nb), u: 1024 tiles. Total 1536, grid 384.
// ---------------------------------------------------------------------------
__global__ __launch_bounds__(256) void mfma_energy2(
    const __bf16* __restrict__ Az, const __bf16* __restrict__ Wz, int ldwz,
    const float* __restrict__ addz, int asz, const float* __restrict__ mulz, int msz,
    float* __restrict__ outz, int Tz,
    const __bf16* __restrict__ Au, const __bf16* __restrict__ Wu, int ldwu,
    const float* __restrict__ addu, int asu, const float* __restrict__ mulu, int msu,
    float* __restrict__ outu, int Tu,
    int ztiles, int ntiles)
{
  const int wv = threadIdx.x >> 6, lane = threadIdx.x & 63;
  const int tile = blockIdx.x*4 + wv;
  if (tile >= ntiles) return;
  const __bf16 *A, *W; const float *add, *mul; float* outp;
  int ldw, as, ms, T, lt;
  if (tile < ztiles) { A=Az; W=Wz; ldw=ldwz; add=addz; as=asz; mul=mulz; ms=msz; outp=outz; T=Tz; lt=tile; }
  else               { A=Au; W=Wu; ldw=ldwu; add=addu; as=asu; mul=mulu; ms=msu; outp=outu; T=Tu; lt=tile-ztiles; }
  const int nb = lt & 7;
  const int bn = nb * 64, bm = (lt >> 3) * 128;
  const int col = lane & 15, g = lane >> 4;
  f32x4 acc[8][4] = {};
  for (int k0 = 0; k0 < 512; k0 += 32) {
    const int k = k0 + g*8;
    bf16x8 af[8], bw[4];
#pragma unroll
    for (int i = 0; i < 8; ++i)
      af[i] = *(const bf16x8*)(A + (size_t)(bm + i*16 + col)*512 + k);
#pragma unroll
    for (int i = 0; i < 4; ++i)
      bw[i] = *(const bf16x8*)(W + (size_t)(bn + i*16 + col)*ldw + k);
#pragma unroll
    for (int mi = 0; mi < 8; ++mi)
#pragma unroll
      for (int ni = 0; ni < 4; ++ni)
        acc[mi][ni] = __builtin_amdgcn_mfma_f32_16x16x32_bf16(af[mi], bw[ni], acc[mi][ni], 0, 0, 0);
  }
#pragma unroll
  for (int mi = 0; mi < 8; ++mi)
#pragma unroll
    for (int r = 0; r < 4; ++r) {
      int m = bm + mi*16 + g*4 + r;
      int b = m & (B_-1), t = m >> 7;
      float p = 0.f;
#pragma unroll
      for (int ni = 0; ni < 4; ++ni) {
        int n = bn + ni*16 + col;
        float v = tanhf(acc[mi][ni][r] + add[(size_t)b*as + n]);
        p += v * mul[(size_t)b*ms + n];
      }
      p += __shfl_xor(p, 1); p += __shfl_xor(p, 2);
      p += __shfl_xor(p, 4); p += __shfl_xor(p, 8);
      if (col == 0) outp[(size_t)nb*(B_*T) + b*T + t] = p;
    }
}

// ---------------------------------------------------------------------------
// Fused: z+u softmax over partials + both contexts (bf16x8-vectorized) +
// concat into gin/cat3b. One block per batch row.
// ---------------------------------------------------------------------------
__global__ __launch_bounds__(256) void attn_ctx_concat(
    const float* __restrict__ partZ, const float* __restrict__ partU,
    const __bf16* __restrict__ zb, const __bf16* __restrict__ ub,
    const int* __restrict__ m_t, const float* __restrict__ emb,
    const float* __restrict__ degree,
    __bf16* __restrict__ gin, __bf16* __restrict__ cat3b)
{
  const int b = blockIdx.x, tid = threadIdx.x;
  __shared__ float sa[256];
  __shared__ float awz[TZ];
  __shared__ float awu[TU];
  __shared__ float szc[H_];
  __shared__ float suc[H_];
  {
    float s = -INFINITY;
    if (tid < TZ) {
      s = 0.f;
#pragma unroll
      for (int nb = 0; nb < NB; ++nb) s += partZ[(size_t)nb*(B_*TZ) + b*TZ + tid];
    }
    sa[tid] = s; __syncthreads();
    for (int o = 128; o > 0; o >>= 1) { if (tid < o) sa[tid] = fmaxf(sa[tid], sa[tid+o]); __syncthreads(); }
    float mx = sa[0]; __syncthreads();
    float e = (tid < TZ) ? __expf(s - mx) : 0.f;
    sa[tid] = e; __syncthreads();
    for (int o = 128; o > 0; o >>= 1) { if (tid < o) sa[tid] += sa[tid+o]; __syncthreads(); }
    float inv = 1.f / sa[0];
    if (tid < TZ) awz[tid] = e * inv;
    __syncthreads();
  }
  {
    float s = -INFINITY;
    if (tid < TU) {
      s = 0.f;
#pragma unroll
      for (int nb = 0; nb < NB; ++nb) s += partU[(size_t)nb*(B_*TU) + b*TU + tid];
    }
    sa[tid] = s; __syncthreads();
    for (int o = 128; o > 0; o >>= 1) { if (tid < o) sa[tid] = fmaxf(sa[tid], sa[tid+o]); __syncthreads(); }
    float mx = sa[0]; __syncthreads();
    float e = (tid < TU) ? __expf(s - mx) : 0.f;
    sa[tid] = e; __syncthreads();
    for (int o = 128; o > 0; o >>= 1) { if (tid < o) sa[tid] += sa[tid+o]; __syncthreads(); }
    float inv = 1.f / sa[0];
    if (tid < TU) awu[tid] = e * inv;
    __syncthreads();
  }
  // contexts: wave 0 -> z (64 t), wave 1 -> u (128 t); 8 h per lane via bf16x8
  {
    const int wvi = tid >> 6, l = tid & 63;
    const int h0 = l * 8;
    if (wvi == 0) {
      float a0=0,a1=0,a2=0,a3=0,a4=0,a5=0,a6=0,a7=0;
      for (int t = 0; t < TZ; ++t) {
        float w = awz[t];
        bf16x8 v = *(const bf16x8*)(zb + ((size_t)t*B_ + b)*H_ + h0);
        a0 += w*(float)v[0]; a1 += w*(float)v[1]; a2 += w*(float)v[2]; a3 += w*(float)v[3];
        a4 += w*(float)v[4]; a5 += w*(float)v[5]; a6 += w*(float)v[6]; a7 += w*(float)v[7];
      }
      szc[h0+0]=a0; szc[h0+1]=a1; szc[h0+2]=a2; szc[h0+3]=a3;
      szc[h0+4]=a4; szc[h0+5]=a5; szc[h0+6]=a6; szc[h0+7]=a7;
    } else if (wvi == 1) {
      float a0=0,a1=0,a2=0,a3=0,a4=0,a5=0,a6=0,a7=0;
      for (int t = 0; t < TU; ++t) {
        float w = awu[t];
        bf16x8 v = *(const bf16x8*)(ub + ((size_t)t*B_ + b)*H_ + h0);
        a0 += w*(float)v[0]; a1 += w*(float)v[1]; a2 += w*(float)v[2]; a3 += w*(float)v[3];
        a4 += w*(float)v[4]; a5 += w*(float)v[5]; a6 += w*(float)v[6]; a7 += w*(float)v[7];
      }
      suc[h0+0]=a0; suc[h0+1]=a1; suc[h0+2]=a2; suc[h0+3]=a3;
      suc[h0+4]=a4; suc[h0+5]=a5; suc[h0+6]=a6; suc[h0+7]=a7;
    }
  }
  __syncthreads();
  const float* e = emb + (size_t)m_t[b] * H_;
  for (int h = tid; h < H_; h += 256) {
    float accz = szc[h], accu = suc[h];
    gin[(size_t)b*GINP + h]          = (__bf16)e[h];
    gin[(size_t)b*GINP + H_ + h]     = (__bf16)accu;
    gin[(size_t)b*GINP + 2*H_ + h]   = (__bf16)accz;
    cat3b[(size_t)b*G3 + h]          = (__bf16)accz;
    cat3b[(size_t)b*G3 + H_ + h]     = (__bf16)accu;
  }
  if (tid < 5) gin[(size_t)b*GINP + 3*H_ + tid] = (__bf16)degree[b*5 + tid];
  if (tid >= 5 && tid < 32) gin[(size_t)b*GINP + GIN + (tid-5)] = (__bf16)0.f;
}

// ---------------------------------------------------------------------------
// GRU input GEMM, K-split x2.
// ---------------------------------------------------------------------------
__global__ __launch_bounds__(256) void mfma_gru(
    const __bf16* __restrict__ A, const __bf16* __restrict__ W,
    float* __restrict__ giA, float* __restrict__ giB)
{
  const int wv = threadIdx.x >> 6, lane = threadIdx.x & 63;
  const int tile = blockIdx.x*4 + wv;
  if (tile >= 96) return;
  const int half = tile / 48, lt = tile % 48;
  const int bn = (lt % 24) * 64, bm = (lt / 24) * 64;
  const int col = lane & 15, g = lane >> 4;
  const int kbeg = half ? 800 : 0, kend_ = half ? GINP : 800;
  float* C = half ? giB : giA;
  f32x4 acc[4][4] = {};
  for (int k0 = kbeg; k0 < kend_; k0 += 32) {
    const int k = k0 + g*8;
    bf16x8 af[4], bw[4];
#pragma unroll
    for (int i = 0; i < 4; ++i) {
      af[i] = *(const bf16x8*)(A + (size_t)(bm + i*16 + col)*GINP + k);
      bw[i] = *(const bf16x8*)(W + (size_t)(bn + i*16 + col)*GINP + k);
    }
#pragma unroll
    for (int i = 0; i < 4; ++i)
#pragma unroll
      for (int j = 0; j < 4; ++j)
        acc[i][j] = __builtin_amdgcn_mfma_f32_16x16x32_bf16(af[i], bw[j], acc[i][j], 0, 0, 0);
  }
#pragma unroll
  for (int mi = 0; mi < 4; ++mi)
#pragma unroll
    for (int r = 0; r < 4; ++r) {
      int m = bm + mi*16 + g*4 + r;
#pragma unroll
      for (int ni = 0; ni < 4; ++ni)
        C[(size_t)m*G3 + bn + ni*16 + col] = acc[mi][ni][r];
    }
}

// ---------------------------------------------------------------------------
// GRU pointwise.
// ---------------------------------------------------------------------------
__global__ __launch_bounds__(256) void gru_kernel(
    const float* __restrict__ giA, const float* __restrict__ giB,
    const float* __restrict__ gh, const float* __restrict__ bih,
    const float* __restrict__ hprev,
    float* __restrict__ hnew, __bf16* __restrict__ cat3b,
    float* __restrict__ out1, float* __restrict__ out2)
{
  int idx = blockIdx.x*256 + threadIdx.x;        // B*H
  int b = idx >> 9, h = idx & (H_-1);
  size_t base = (size_t)b*G3;
  float ir = giA[base + h]        + giB[base + h]        + bih[h]        + gh[base + h];
  float iz = giA[base + H_ + h]   + giB[base + H_ + h]   + bih[H_ + h]   + gh[base + H_ + h];
  float in_= giA[base + 2*H_ + h] + giB[base + 2*H_ + h] + bih[2*H_ + h];
  float hn = gh[base + 2*H_ + h];
  float r = sigmoidf_(ir);
  float z = sigmoidf_(iz);
  float n = tanhf(in_ + r*hn);
  float hv = (1.f - z)*n + z*hprev[idx];
  hnew[idx] = hv;
  cat3b[base + 2*H_ + h] = (__bf16)hv;
  out1[idx] = hv;
  out2[idx] = hv;
}

// ---------------------------------------------------------------------------
// Fused projection (K-split x3, bf16 W, 750 tiles) + copy-energy (1024 tiles).
// (R8 configuration.)
// ---------------------------------------------------------------------------
__global__ __launch_bounds__(256) void proj_copy(
    const __bf16* __restrict__ cat3b, const __bf16* __restrict__ pWb, float* __restrict__ P,
    const __bf16* __restrict__ zb, const __bf16* __restrict__ cWb,
    const float* __restrict__ c2b, const float* __restrict__ hnew,
    float* __restrict__ partC)
{
  const int wv = threadIdx.x >> 6, lane = threadIdx.x & 63;
  const int tile = blockIdx.x*4 + wv;
  const int col = lane & 15, g = lane >> 4;
  if (tile < 750) {
    const int s = tile / 250, t2 = tile % 250;
    const int bn = (t2 % 125) * 64, bm = (t2 / 125) * 64;
    const __bf16* As = cat3b + s*512;
    const __bf16* Ws = pWb + s*512;
    float* C = P + (size_t)s*B_*V_;
    f32x4 acc[4][4] = {};
    for (int k0 = 0; k0 < 512; k0 += 32) {
      const int k = k0 + g*8;
      bf16x8 af[4], bw[4];
#pragma unroll
      for (int i = 0; i < 4; ++i) {
        af[i] = *(const bf16x8*)(As + (size_t)(bm + i*16 + col)*G3 + k);
        bw[i] = *(const bf16x8*)(Ws + (size_t)(bn + i*16 + col)*G3 + k);
      }
#pragma unroll
      for (int i = 0; i < 4; ++i)
#pragma unroll
        for (int j = 0; j < 4; ++j)
          acc[i][j] = __builtin_amdgcn_mfma_f32_16x16x32_bf16(af[i], bw[j], acc[i][j], 0, 0, 0);
    }
#pragma unroll
    for (int mi = 0; mi < 4; ++mi)
#pragma unroll
      for (int r = 0; r < 4; ++r) {
        int m = bm + mi*16 + g*4 + r;
#pragma unroll
        for (int ni = 0; ni < 4; ++ni)
          C[(size_t)m*V_ + bn + ni*16 + col] = acc[mi][ni][r];
      }
  } else if (tile < 750 + 1024) {
    const int lt = tile - 750;
    const int nb = lt & 7;
    const int bn = nb * 64, bm = (lt >> 3) * 64;
    f32x4 acc[4][4] = {};
    for (int k0 = 0; k0 < 512; k0 += 32) {
      const int k = k0 + g*8;
      bf16x8 af[4], bw[4];
#pragma unroll
      for (int i = 0; i < 4; ++i) {
        af[i] = *(const bf16x8*)(zb + (size_t)(bm + i*16 + col)*512 + k);
        bw[i] = *(const bf16x8*)(cWb + (size_t)(bn + i*16 + col)*H_ + k);
      }
#pragma unroll
      for (int i = 0; i < 4; ++i)
#pragma unroll
        for (int j = 0; j < 4; ++j)
          acc[i][j] = __builtin_amdgcn_mfma_f32_16x16x32_bf16(af[i], bw[j], acc[i][j], 0, 0, 0);
    }
#pragma unroll
    for (int mi = 0; mi < 4; ++mi)
#pragma unroll
      for (int r = 0; r < 4; ++r) {
        int m = bm + mi*16 + g*4 + r;
        int b = m & (B_-1), t = m >> 7;
        float p = 0.f;
#pragma unroll
        for (int ni = 0; ni < 4; ++ni) {
          int n = bn + ni*16 + col;
          float v = tanhf(acc[mi][ni][r] + c2b[n]);
          p += v * hnew[(size_t)b*H_ + n];
        }
        p += __shfl_xor(p, 1); p += __shfl_xor(p, 2);
        p += __shfl_xor(p, 4); p += __shfl_xor(p, 8);
        if (col == 0) partC[(size_t)nb*(B_*TZ) + b*TZ + t] = p;
      }
  }
}

// ---------------------------------------------------------------------------
// zcopy with folded zexp.
// ---------------------------------------------------------------------------
__global__ __launch_bounds__(256) void zcopy_kernel(
    const float* __restrict__ partC, const float* __restrict__ sr,
    float* __restrict__ zbuf)
{
  const int b = blockIdx.y, tid = threadIdx.x;
  __shared__ float se[TZ];
  __shared__ float smx;
  if (tid < TZ) {
    float s = 0.f;
#pragma unroll
    for (int nb = 0; nb < NB; ++nb) s += partC[(size_t)nb*(B_*TZ) + b*TZ + tid];
    float mx = s;
    mx = fmaxf(mx, __shfl_xor(mx, 1));  mx = fmaxf(mx, __shfl_xor(mx, 2));
    mx = fmaxf(mx, __shfl_xor(mx, 4));  mx = fmaxf(mx, __shfl_xor(mx, 8));
    mx = fmaxf(mx, __shfl_xor(mx, 16)); mx = fmaxf(mx, __shfl_xor(mx, 32));
    se[tid] = __expf(s - mx);
    if (tid == 0) smx = mx;
  }
  __syncthreads();
  const int v0 = blockIdx.x*1024 + tid*4;
  if (v0 >= VC) return;
  float4 acc = {0.f, 0.f, 0.f, 0.f};
  const float* base = sr + (size_t)b*TZ*VC;
#pragma unroll 4
  for (int t = 0; t < TZ; ++t) {
    float et = se[t];
    float4 x = *(const float4*)(base + (size_t)t*VC + v0);
    acc.x += et*x.x; acc.y += et*x.y; acc.z += et*x.z; acc.w += et*x.w;
  }
  float m = smx;
  float* out = zbuf + (size_t)b*VC + v0;
  out[0] = __logf(acc.x) + m;
  out[1] = __logf(acc.y) + m;
  out[2] = __logf(acc.z) + m;
  out[3] = __logf(acc.w) + m;
}

// ---------------------------------------------------------------------------
// Final softmax (3-pass, R8 version).
// ---------------------------------------------------------------------------
__global__ __launch_bounds__(256) void final_softmax2(
    const float* __restrict__ p0, const float* __restrict__ p1, const float* __restrict__ p2,
    const float* __restrict__ bias, const float* __restrict__ zbuf, float* __restrict__ out0)
{
  const int b = blockIdx.x, tid = threadIdx.x;
  const float* q0 = p0 + (size_t)b*V_;
  const float* q1 = p1 + (size_t)b*V_;
  const float* q2 = p2 + (size_t)b*V_;
  const float* zr = zbuf + (size_t)b*VC;
  __shared__ float sa[256];
  float mx = -INFINITY;
  for (int i = tid; i < V_; i += 256) mx = fmaxf(mx, q0[i]+q1[i]+q2[i]+bias[i]);
  for (int i = tid; i < VC; i += 256) mx = fmaxf(mx, zr[i]);
  sa[tid] = mx; __syncthreads();
  for (int o = 128; o > 0; o >>= 1) { if (tid < o) sa[tid] = fmaxf(sa[tid], sa[tid+o]); __syncthreads(); }
  mx = sa[0]; __syncthreads();
  float sum = 0.f;
  for (int i = tid; i < V_; i += 256) sum += __expf(q0[i]+q1[i]+q2[i]+bias[i] - mx);
  for (int i = tid; i < VC; i += 256) sum += __expf(zr[i] - mx);
  sa[tid] = sum; __syncthreads();
  for (int o = 128; o > 0; o >>= 1) { if (tid < o) sa[tid] += sa[tid+o]; __syncthreads(); }
  float inv = 1.f / sa[0];
  float* o0 = out0 + (size_t)b*VC;
  for (int j = tid; j < V_; j += 256)
    o0[j] = (__expf(q0[j]+q1[j]+q2[j]+bias[j]-mx) + __expf(zr[j]-mx)) * inv;
  for (int j = tid; j < TZ; j += 256)
    o0[V_ + j] = __expf(zr[V_ + j] - mx) * inv;
}

// ---------------------------------------------------------------------------
extern "C" void kernel_launch(void* const* d_in, const int* in_sizes, int n_in,
                              void* d_out, int out_size, void* d_ws, size_t ws_size,
                              hipStream_t stream)
{
  const float* z_enc   = (const float*)d_in[0];
  const float* u_enc   = (const float*)d_in[1];
  const int*   m_t     = (const int*)  d_in[2];
  const float* degree  = (const float*)d_in[3];
  const float* hidden  = (const float*)d_in[4];
  const float* sr      = (const float*)d_in[5];
  const float* emb     = (const float*)d_in[6];
  const float* attn_z_W= (const float*)d_in[7];
  const float* attn_z_b= (const float*)d_in[8];
  const float* attn_z_v= (const float*)d_in[9];
  const float* attn_u_W= (const float*)d_in[10];
  const float* attn_u_b= (const float*)d_in[11];
  const float* attn_u_v= (const float*)d_in[12];
  const float* gru_W_ih= (const float*)d_in[13];
  const float* gru_W_hh= (const float*)d_in[14];
  const float* gru_b_ih= (const float*)d_in[15];
  const float* gru_b_hh= (const float*)d_in[16];
  const float* proj_W  = (const float*)d_in[17];
  const float* proj_b  = (const float*)d_in[18];
  const float* copy2_W = (const float*)d_in[19];
  const float* copy2_b = (const float*)d_in[20];

  float* out0 = (float*)d_out;
  float* out1 = out0 + (size_t)B_*VC;
  float* out2 = out1 + (size_t)B_*H_;

  // Workspace — fp32 region
  float* ws    = (float*)d_ws;
  float* hWz   = ws;
  float* hWu   = hWz   + B_*H_;
  float* gh    = hWu   + B_*H_;
  float* partZ = gh    + B_*G3;
  float* partU = partZ + NB*B_*TZ;
  float* partC = partU + NB*B_*TU;
  float* giA   = partC + NB*B_*TZ;
  float* giB   = giA   + B_*G3;
  float* hnew  = giB   + B_*G3;
  float* p0    = hnew  + B_*H_;
  float* p1    = p0    + (size_t)B_*V_;
  float* p2    = p1    + (size_t)B_*V_;
  float* zbuf  = p2    + (size_t)B_*V_;
  // bf16 region
  __bf16* gin   = (__bf16*)(zbuf + (size_t)B_*VC);
  __bf16* Wp    = gin   + (size_t)B_*GINP;
  __bf16* zb    = Wp    + (size_t)G3*GINP;
  __bf16* ub    = zb    + (size_t)TZ*B_*H_;
  __bf16* hb    = ub    + (size_t)TU*B_*H_;
  __bf16* zWb   = hb    + (size_t)B_*H_;
  __bf16* uWb   = zWb   + (size_t)H_*2*H_;
  __bf16* cWb   = uWb   + (size_t)H_*2*H_;
  __bf16* whhb  = cWb   + (size_t)H_*H_;
  __bf16* pWb   = whhb  + (size_t)G3*H_;
  __bf16* cat3b = pWb   + (size_t)V_*G3;

  // 1. convert everything to bf16 (incl. proj_W and padded gru_W_ih)
  cvt_all<<<(CVT_UNITS + 255)/256, 256, 0, stream>>>(
      z_enc, u_enc, hidden, attn_z_W, attn_u_W, copy2_W, gru_W_hh, proj_W, gru_W_ih,
      zb, ub, hb, zWb, uWb, cWb, whhb, pWb, Wp);

  // 2. fused hidden-side GEMMs
  hidden3<<<20, 256, 0, stream>>>(hb, zWb, attn_z_b, hWz, uWb, attn_u_b, hWu, whhb, gru_b_hh, gh);

  // 3. fused z+u attention energies (128-row tiles: z 512, u 1024 -> 1536)
  mfma_energy2<<<384, 256, 0, stream>>>(
      zb, zWb + H_, 2*H_, hWz, H_, attn_z_v, 0, partZ, TZ,
      ub, uWb + H_, 2*H_, hWu, H_, attn_u_v, 0, partU, TU,
      512, 1536);

  // 4. fused softmax + context (vectorized) + concat
  attn_ctx_concat<<<B_, 256, 0, stream>>>(partZ, partU, zb, ub, m_t, emb, degree, gin, cat3b);

  // 5. GRU input GEMM (K-split x2) + pointwise
  mfma_gru<<<24, 256, 0, stream>>>(gin, Wp, giA, giB);
  gru_kernel<<<(B_*H_)/256, 256, 0, stream>>>(giA, giB, gh, gru_b_ih, hidden, hnew, cat3b, out1, out2);

  // 6. fused projection + copy-energy (1774 tiles)
  proj_copy<<<444, 256, 0, stream>>>(cat3b, pWb, p0, zb, cWb, copy2_b, hnew, partC);

  // 7. zcopy (zexp folded in)
  zcopy_kernel<<<dim3((VC + 1023)/1024, B_), 256, 0, stream>>>(partC, sr, zbuf);

  // 8. final softmax + output assembly
  final_softmax2<<<B_, 256, 0, stream>>>(p0, p1, p2, proj_b, zbuf, out0);
}

// Round 12
// 297.231 us; speedup vs baseline: 1.1739x; 1.1739x over previous
//
#include <hip/hip_runtime.h>
#include <hip/hip_bf16.h>
#include <math.h>

// Problem constants
#define B_   128
#define H_   512
#define TZ   64
#define TU   128
#define V_   8000
#define VC   8064            // V + TZ
#define GIN  1541            // E + 2H + 5
#define GINP 1568            // GIN padded to multiple of 32
#define G3   1536            // 3*H
#define NB   8               // n-blocks per 512-wide energy GEMM

typedef float f32x4 __attribute__((ext_vector_type(4)));
typedef __bf16 bf16x8 __attribute__((ext_vector_type(8)));

__device__ __forceinline__ float sigmoidf_(float x){ return 1.f/(1.f+__expf(-x)); }

__device__ __forceinline__ bf16x8 load8_bf16(const float* __restrict__ p){
  float4 x = *(const float4*)p;
  float4 y = *(const float4*)(p+4);
  bf16x8 r;
  r[0]=(__bf16)x.x; r[1]=(__bf16)x.y; r[2]=(__bf16)x.z; r[3]=(__bf16)x.w;
  r[4]=(__bf16)y.x; r[5]=(__bf16)y.y; r[6]=(__bf16)y.z; r[7]=(__bf16)y.w;
  return r;
}
__device__ __forceinline__ void cvt8(const float* __restrict__ s, __bf16* __restrict__ d){
  *(bf16x8*)d = load8_bf16(s);
}

// ---------------------------------------------------------------------------
// One-pass fp32->bf16 conversion of all MFMA operands (unit = 8 elems),
// including gru_W_ih with row padding 1541 -> 1568 (R8 config).
// ---------------------------------------------------------------------------
#define U_Z   524288u     // z_enc
#define U_U   1048576u    // u_enc
#define U_H   8192u       // hidden
#define U_ZW  65536u      // attn_z_W
#define U_UW  65536u      // attn_u_W
#define U_CW  32768u      // copy2_W
#define U_WHH 98304u      // gru_W_hh
#define U_PW  1536000u    // proj_W
#define U_WIH 301056u     // gru_W_ih padded: 1536*1568/8
#define CVT_UNITS (U_Z+U_U+U_H+U_ZW+U_UW+U_CW+U_WHH+U_PW+U_WIH)

__global__ __launch_bounds__(256) void cvt_all(
    const float* __restrict__ z, const float* __restrict__ u, const float* __restrict__ hid,
    const float* __restrict__ zW, const float* __restrict__ uW, const float* __restrict__ cW,
    const float* __restrict__ whh, const float* __restrict__ pW, const float* __restrict__ wih,
    __bf16* __restrict__ zb, __bf16* __restrict__ ub, __bf16* __restrict__ hb,
    __bf16* __restrict__ zWb, __bf16* __restrict__ uWb, __bf16* __restrict__ cWb,
    __bf16* __restrict__ whhb, __bf16* __restrict__ pWb, __bf16* __restrict__ Wp)
{
  unsigned t = blockIdx.x*256u + threadIdx.x;
  if (t >= CVT_UNITS) return;
  unsigned o = t;
  if (o >= CVT_UNITS - U_WIH) {           // gru_W_ih pad segment (scalar loads)
    o -= (CVT_UNITS - U_WIH);
    unsigned r = o / (GINP/8), cu = o % (GINP/8);
    int c0 = cu*8;
    const float* src = wih + (size_t)r*GIN;
    bf16x8 v;
#pragma unroll
    for (int e = 0; e < 8; ++e) {
      int c = c0 + e;
      v[e] = (__bf16)((c < GIN) ? src[c] : 0.f);
    }
    *(bf16x8*)(Wp + (size_t)r*GINP + c0) = v;
    return;
  }
  const float* s; __bf16* d;
  if      (o < U_Z)                   { s=z;   d=zb;   }
  else if ((o-=U_Z)   < U_U)          { s=u;   d=ub;   }
  else if ((o-=U_U)   < U_H)          { s=hid; d=hb;   }
  else if ((o-=U_H)   < U_ZW)         { s=zW;  d=zWb;  }
  else if ((o-=U_ZW)  < U_UW)         { s=uW;  d=uWb;  }
  else if ((o-=U_UW)  < U_CW)         { s=cW;  d=cWb;  }
  else if ((o-=U_CW)  < U_WHH)        { s=whh; d=whhb; }
  else     { o-=U_WHH;                  s=pW;  d=pWb;  }
  cvt8(s + (size_t)o*8, d + (size_t)o*8);
}

// ---------------------------------------------------------------------------
// Fused hidden-side GEMMs: hWz (16 tiles), hWu (16), gh (48). 80 tiles total.
// ---------------------------------------------------------------------------
__global__ __launch_bounds__(256) void hidden3(
    const __bf16* __restrict__ hb,
    const __bf16* __restrict__ zWb, const float* __restrict__ zbias, float* __restrict__ hWz,
    const __bf16* __restrict__ uWb, const float* __restrict__ ubias, float* __restrict__ hWu,
    const __bf16* __restrict__ whhb, const float* __restrict__ hbias, float* __restrict__ gh)
{
  const int wv = threadIdx.x >> 6, lane = threadIdx.x & 63;
  const int tile = blockIdx.x*4 + wv;
  if (tile >= 80) return;
  const __bf16* W; const float* bias; float* C; int ldw, ldc, nbn, lt;
  if (tile < 16)      { W=zWb;  bias=zbias; C=hWz; ldw=2*H_; ldc=H_; nbn=8;  lt=tile; }
  else if (tile < 32) { W=uWb;  bias=ubias; C=hWu; ldw=2*H_; ldc=H_; nbn=8;  lt=tile-16; }
  else                { W=whhb; bias=hbias; C=gh;  ldw=H_;   ldc=G3; nbn=24; lt=tile-32; }
  const int bn = (lt % nbn) * 64, bm = (lt / nbn) * 64;
  const int col = lane & 15, g = lane >> 4;
  f32x4 acc[4][4] = {};
  for (int k0 = 0; k0 < 512; k0 += 32) {
    const int k = k0 + g*8;
    bf16x8 af[4], bw[4];
#pragma unroll
    for (int i = 0; i < 4; ++i) {
      af[i] = *(const bf16x8*)(hb + (size_t)(bm + i*16 + col)*H_ + k);
      bw[i] = *(const bf16x8*)(W  + (size_t)(bn + i*16 + col)*ldw + k);
    }
#pragma unroll
    for (int i = 0; i < 4; ++i)
#pragma unroll
      for (int j = 0; j < 4; ++j)
        acc[i][j] = __builtin_amdgcn_mfma_f32_16x16x32_bf16(af[i], bw[j], acc[i][j], 0, 0, 0);
  }
#pragma unroll
  for (int mi = 0; mi < 4; ++mi)
#pragma unroll
    for (int r = 0; r < 4; ++r) {
      int m = bm + mi*16 + g*4 + r;
#pragma unroll
      for (int ni = 0; ni < 4; ++ni) {
        int n = bn + ni*16 + col;
        C[(size_t)m*ldc + n] = acc[mi][ni][r] + bias[n];
      }
    }
}

// ---------------------------------------------------------------------------
// Fused z+u attention energies (bf16), R8 structure (acc[4][4], 3072 tiles).
//   partial[nb][b*T+t] = sum_{n in nb} tanh(acc + add[b*as+n]) * mul[b*ms+n]
// ---------------------------------------------------------------------------
__global__ __launch_bounds__(256) void mfma_energy2(
    const __bf16* __restrict__ Az, const __bf16* __restrict__ Wz, int ldwz,
    const float* __restrict__ addz, int asz, const float* __restrict__ mulz, int msz,
    float* __restrict__ outz, int Tz,
    const __bf16* __restrict__ Au, const __bf16* __restrict__ Wu, int ldwu,
    const float* __restrict__ addu, int asu, const float* __restrict__ mulu, int msu,
    float* __restrict__ outu, int Tu,
    int ztiles, int ntiles)
{
  const int wv = threadIdx.x >> 6, lane = threadIdx.x & 63;
  const int tile = blockIdx.x*4 + wv;
  if (tile >= ntiles) return;
  const __bf16 *A, *W; const float *add, *mul; float* outp;
  int ldw, as, ms, T, lt;
  if (tile < ztiles) { A=Az; W=Wz; ldw=ldwz; add=addz; as=asz; mul=mulz; ms=msz; outp=outz; T=Tz; lt=tile; }
  else               { A=Au; W=Wu; ldw=ldwu; add=addu; as=asu; mul=mulu; ms=msu; outp=outu; T=Tu; lt=tile-ztiles; }
  const int nb = lt & 7;
  const int bn = nb * 64, bm = (lt >> 3) * 64;
  const int col = lane & 15, g = lane >> 4;
  f32x4 acc[4][4] = {};
  for (int k0 = 0; k0 < 512; k0 += 32) {
    const int k = k0 + g*8;
    bf16x8 af[4], bw[4];
#pragma unroll
    for (int i = 0; i < 4; ++i) {
      af[i] = *(const bf16x8*)(A + (size_t)(bm + i*16 + col)*512 + k);
      bw[i] = *(const bf16x8*)(W + (size_t)(bn + i*16 + col)*ldw + k);
    }
#pragma unroll
    for (int i = 0; i < 4; ++i)
#pragma unroll
      for (int j = 0; j < 4; ++j)
        acc[i][j] = __builtin_amdgcn_mfma_f32_16x16x32_bf16(af[i], bw[j], acc[i][j], 0, 0, 0);
  }
#pragma unroll
  for (int mi = 0; mi < 4; ++mi)
#pragma unroll
    for (int r = 0; r < 4; ++r) {
      int m = bm + mi*16 + g*4 + r;
      int b = m & (B_-1), t = m >> 7;
      float p = 0.f;
#pragma unroll
      for (int ni = 0; ni < 4; ++ni) {
        int n = bn + ni*16 + col;
        float v = tanhf(acc[mi][ni][r] + add[(size_t)b*as + n]);
        p += v * mul[(size_t)b*ms + n];
      }
      p += __shfl_xor(p, 1); p += __shfl_xor(p, 2);
      p += __shfl_xor(p, 4); p += __shfl_xor(p, 8);
      if (col == 0) outp[(size_t)nb*(B_*T) + b*T + t] = p;
    }
}

// ---------------------------------------------------------------------------
// Fused: z+u softmax over partials + both contexts (bf16x8-vectorized) +
// concat into gin/cat3b. One block per batch row. [only change vs R8]
// ---------------------------------------------------------------------------
__global__ __launch_bounds__(256) void attn_ctx_concat(
    const float* __restrict__ partZ, const float* __restrict__ partU,
    const __bf16* __restrict__ zb, const __bf16* __restrict__ ub,
    const int* __restrict__ m_t, const float* __restrict__ emb,
    const float* __restrict__ degree,
    __bf16* __restrict__ gin, __bf16* __restrict__ cat3b)
{
  const int b = blockIdx.x, tid = threadIdx.x;
  __shared__ float sa[256];
  __shared__ float awz[TZ];
  __shared__ float awu[TU];
  __shared__ float szc[H_];
  __shared__ float suc[H_];
  {
    float s = -INFINITY;
    if (tid < TZ) {
      s = 0.f;
#pragma unroll
      for (int nb = 0; nb < NB; ++nb) s += partZ[(size_t)nb*(B_*TZ) + b*TZ + tid];
    }
    sa[tid] = s; __syncthreads();
    for (int o = 128; o > 0; o >>= 1) { if (tid < o) sa[tid] = fmaxf(sa[tid], sa[tid+o]); __syncthreads(); }
    float mx = sa[0]; __syncthreads();
    float e = (tid < TZ) ? __expf(s - mx) : 0.f;
    sa[tid] = e; __syncthreads();
    for (int o = 128; o > 0; o >>= 1) { if (tid < o) sa[tid] += sa[tid+o]; __syncthreads(); }
    float inv = 1.f / sa[0];
    if (tid < TZ) awz[tid] = e * inv;
    __syncthreads();
  }
  {
    float s = -INFINITY;
    if (tid < TU) {
      s = 0.f;
#pragma unroll
      for (int nb = 0; nb < NB; ++nb) s += partU[(size_t)nb*(B_*TU) + b*TU + tid];
    }
    sa[tid] = s; __syncthreads();
    for (int o = 128; o > 0; o >>= 1) { if (tid < o) sa[tid] = fmaxf(sa[tid], sa[tid+o]); __syncthreads(); }
    float mx = sa[0]; __syncthreads();
    float e = (tid < TU) ? __expf(s - mx) : 0.f;
    sa[tid] = e; __syncthreads();
    for (int o = 128; o > 0; o >>= 1) { if (tid < o) sa[tid] += sa[tid+o]; __syncthreads(); }
    float inv = 1.f / sa[0];
    if (tid < TU) awu[tid] = e * inv;
    __syncthreads();
  }
  // contexts: wave 0 -> z, wave 1 -> u; 8 h per lane via bf16x8 loads
  {
    const int wvi = tid >> 6, l = tid & 63;
    const int h0 = l * 8;
    if (wvi == 0) {
      float a0=0,a1=0,a2=0,a3=0,a4=0,a5=0,a6=0,a7=0;
      for (int t = 0; t < TZ; ++t) {
        float w = awz[t];
        bf16x8 v = *(const bf16x8*)(zb + ((size_t)t*B_ + b)*H_ + h0);
        a0 += w*(float)v[0]; a1 += w*(float)v[1]; a2 += w*(float)v[2]; a3 += w*(float)v[3];
        a4 += w*(float)v[4]; a5 += w*(float)v[5]; a6 += w*(float)v[6]; a7 += w*(float)v[7];
      }
      szc[h0+0]=a0; szc[h0+1]=a1; szc[h0+2]=a2; szc[h0+3]=a3;
      szc[h0+4]=a4; szc[h0+5]=a5; szc[h0+6]=a6; szc[h0+7]=a7;
    } else if (wvi == 1) {
      float a0=0,a1=0,a2=0,a3=0,a4=0,a5=0,a6=0,a7=0;
      for (int t = 0; t < TU; ++t) {
        float w = awu[t];
        bf16x8 v = *(const bf16x8*)(ub + ((size_t)t*B_ + b)*H_ + h0);
        a0 += w*(float)v[0]; a1 += w*(float)v[1]; a2 += w*(float)v[2]; a3 += w*(float)v[3];
        a4 += w*(float)v[4]; a5 += w*(float)v[5]; a6 += w*(float)v[6]; a7 += w*(float)v[7];
      }
      suc[h0+0]=a0; suc[h0+1]=a1; suc[h0+2]=a2; suc[h0+3]=a3;
      suc[h0+4]=a4; suc[h0+5]=a5; suc[h0+6]=a6; suc[h0+7]=a7;
    }
  }
  __syncthreads();
  const float* e = emb + (size_t)m_t[b] * H_;
  for (int h = tid; h < H_; h += 256) {
    float accz = szc[h], accu = suc[h];
    gin[(size_t)b*GINP + h]          = (__bf16)e[h];
    gin[(size_t)b*GINP + H_ + h]     = (__bf16)accu;
    gin[(size_t)b*GINP + 2*H_ + h]   = (__bf16)accz;
    cat3b[(size_t)b*G3 + h]          = (__bf16)accz;
    cat3b[(size_t)b*G3 + H_ + h]     = (__bf16)accu;
  }
  if (tid < 5) gin[(size_t)b*GINP + 3*H_ + tid] = (__bf16)degree[b*5 + tid];
  if (tid >= 5 && tid < 32) gin[(size_t)b*GINP + GIN + (tid-5)] = (__bf16)0.f;
}

// ---------------------------------------------------------------------------
// GRU input GEMM, K-split x2.
// ---------------------------------------------------------------------------
__global__ __launch_bounds__(256) void mfma_gru(
    const __bf16* __restrict__ A, const __bf16* __restrict__ W,
    float* __restrict__ giA, float* __restrict__ giB)
{
  const int wv = threadIdx.x >> 6, lane = threadIdx.x & 63;
  const int tile = blockIdx.x*4 + wv;
  if (tile >= 96) return;
  const int half = tile / 48, lt = tile % 48;
  const int bn = (lt % 24) * 64, bm = (lt / 24) * 64;
  const int col = lane & 15, g = lane >> 4;
  const int kbeg = half ? 800 : 0, kend_ = half ? GINP : 800;
  float* C = half ? giB : giA;
  f32x4 acc[4][4] = {};
  for (int k0 = kbeg; k0 < kend_; k0 += 32) {
    const int k = k0 + g*8;
    bf16x8 af[4], bw[4];
#pragma unroll
    for (int i = 0; i < 4; ++i) {
      af[i] = *(const bf16x8*)(A + (size_t)(bm + i*16 + col)*GINP + k);
      bw[i] = *(const bf16x8*)(W + (size_t)(bn + i*16 + col)*GINP + k);
    }
#pragma unroll
    for (int i = 0; i < 4; ++i)
#pragma unroll
      for (int j = 0; j < 4; ++j)
        acc[i][j] = __builtin_amdgcn_mfma_f32_16x16x32_bf16(af[i], bw[j], acc[i][j], 0, 0, 0);
  }
#pragma unroll
  for (int mi = 0; mi < 4; ++mi)
#pragma unroll
    for (int r = 0; r < 4; ++r) {
      int m = bm + mi*16 + g*4 + r;
#pragma unroll
      for (int ni = 0; ni < 4; ++ni)
        C[(size_t)m*G3 + bn + ni*16 + col] = acc[mi][ni][r];
    }
}

// ---------------------------------------------------------------------------
// GRU pointwise.
// ---------------------------------------------------------------------------
__global__ __launch_bounds__(256) void gru_kernel(
    const float* __restrict__ giA, const float* __restrict__ giB,
    const float* __restrict__ gh, const float* __restrict__ bih,
    const float* __restrict__ hprev,
    float* __restrict__ hnew, __bf16* __restrict__ cat3b,
    float* __restrict__ out1, float* __restrict__ out2)
{
  int idx = blockIdx.x*256 + threadIdx.x;        // B*H
  int b = idx >> 9, h = idx & (H_-1);
  size_t base = (size_t)b*G3;
  float ir = giA[base + h]        + giB[base + h]        + bih[h]        + gh[base + h];
  float iz = giA[base + H_ + h]   + giB[base + H_ + h]   + bih[H_ + h]   + gh[base + H_ + h];
  float in_= giA[base + 2*H_ + h] + giB[base + 2*H_ + h] + bih[2*H_ + h];
  float hn = gh[base + 2*H_ + h];
  float r = sigmoidf_(ir);
  float z = sigmoidf_(iz);
  float n = tanhf(in_ + r*hn);
  float hv = (1.f - z)*n + z*hprev[idx];
  hnew[idx] = hv;
  cat3b[base + 2*H_ + h] = (__bf16)hv;
  out1[idx] = hv;
  out2[idx] = hv;
}

// ---------------------------------------------------------------------------
// Fused projection (K-split x3, bf16 W, 750 tiles) + copy-energy (1024 tiles).
// ---------------------------------------------------------------------------
__global__ __launch_bounds__(256) void proj_copy(
    const __bf16* __restrict__ cat3b, const __bf16* __restrict__ pWb, float* __restrict__ P,
    const __bf16* __restrict__ zb, const __bf16* __restrict__ cWb,
    const float* __restrict__ c2b, const float* __restrict__ hnew,
    float* __restrict__ partC)
{
  const int wv = threadIdx.x >> 6, lane = threadIdx.x & 63;
  const int tile = blockIdx.x*4 + wv;
  const int col = lane & 15, g = lane >> 4;
  if (tile < 750) {
    const int s = tile / 250, t2 = tile % 250;
    const int bn = (t2 % 125) * 64, bm = (t2 / 125) * 64;
    const __bf16* As = cat3b + s*512;
    const __bf16* Ws = pWb + s*512;
    float* C = P + (size_t)s*B_*V_;
    f32x4 acc[4][4] = {};
    for (int k0 = 0; k0 < 512; k0 += 32) {
      const int k = k0 + g*8;
      bf16x8 af[4], bw[4];
#pragma unroll
      for (int i = 0; i < 4; ++i) {
        af[i] = *(const bf16x8*)(As + (size_t)(bm + i*16 + col)*G3 + k);
        bw[i] = *(const bf16x8*)(Ws + (size_t)(bn + i*16 + col)*G3 + k);
      }
#pragma unroll
      for (int i = 0; i < 4; ++i)
#pragma unroll
        for (int j = 0; j < 4; ++j)
          acc[i][j] = __builtin_amdgcn_mfma_f32_16x16x32_bf16(af[i], bw[j], acc[i][j], 0, 0, 0);
    }
#pragma unroll
    for (int mi = 0; mi < 4; ++mi)
#pragma unroll
      for (int r = 0; r < 4; ++r) {
        int m = bm + mi*16 + g*4 + r;
#pragma unroll
        for (int ni = 0; ni < 4; ++ni)
          C[(size_t)m*V_ + bn + ni*16 + col] = acc[mi][ni][r];
      }
  } else if (tile < 750 + 1024) {
    const int lt = tile - 750;
    const int nb = lt & 7;
    const int bn = nb * 64, bm = (lt >> 3) * 64;
    f32x4 acc[4][4] = {};
    for (int k0 = 0; k0 < 512; k0 += 32) {
      const int k = k0 + g*8;
      bf16x8 af[4], bw[4];
#pragma unroll
      for (int i = 0; i < 4; ++i) {
        af[i] = *(const bf16x8*)(zb + (size_t)(bm + i*16 + col)*512 + k);
        bw[i] = *(const bf16x8*)(cWb + (size_t)(bn + i*16 + col)*H_ + k);
      }
#pragma unroll
      for (int i = 0; i < 4; ++i)
#pragma unroll
        for (int j = 0; j < 4; ++j)
          acc[i][j] = __builtin_amdgcn_mfma_f32_16x16x32_bf16(af[i], bw[j], acc[i][j], 0, 0, 0);
    }
#pragma unroll
    for (int mi = 0; mi < 4; ++mi)
#pragma unroll
      for (int r = 0; r < 4; ++r) {
        int m = bm + mi*16 + g*4 + r;
        int b = m & (B_-1), t = m >> 7;
        float p = 0.f;
#pragma unroll
        for (int ni = 0; ni < 4; ++ni) {
          int n = bn + ni*16 + col;
          float v = tanhf(acc[mi][ni][r] + c2b[n]);
          p += v * hnew[(size_t)b*H_ + n];
        }
        p += __shfl_xor(p, 1); p += __shfl_xor(p, 2);
        p += __shfl_xor(p, 4); p += __shfl_xor(p, 8);
        if (col == 0) partC[(size_t)nb*(B_*TZ) + b*TZ + t] = p;
      }
  }
}

// ---------------------------------------------------------------------------
// zcopy with folded zexp.
// ---------------------------------------------------------------------------
__global__ __launch_bounds__(256) void zcopy_kernel(
    const float* __restrict__ partC, const float* __restrict__ sr,
    float* __restrict__ zbuf)
{
  const int b = blockIdx.y, tid = threadIdx.x;
  __shared__ float se[TZ];
  __shared__ float smx;
  if (tid < TZ) {
    float s = 0.f;
#pragma unroll
    for (int nb = 0; nb < NB; ++nb) s += partC[(size_t)nb*(B_*TZ) + b*TZ + tid];
    float mx = s;
    mx = fmaxf(mx, __shfl_xor(mx, 1));  mx = fmaxf(mx, __shfl_xor(mx, 2));
    mx = fmaxf(mx, __shfl_xor(mx, 4));  mx = fmaxf(mx, __shfl_xor(mx, 8));
    mx = fmaxf(mx, __shfl_xor(mx, 16)); mx = fmaxf(mx, __shfl_xor(mx, 32));
    se[tid] = __expf(s - mx);
    if (tid == 0) smx = mx;
  }
  __syncthreads();
  const int v0 = blockIdx.x*1024 + tid*4;
  if (v0 >= VC) return;
  float4 acc = {0.f, 0.f, 0.f, 0.f};
  const float* base = sr + (size_t)b*TZ*VC;
#pragma unroll 4
  for (int t = 0; t < TZ; ++t) {
    float et = se[t];
    float4 x = *(const float4*)(base + (size_t)t*VC + v0);
    acc.x += et*x.x; acc.y += et*x.y; acc.z += et*x.z; acc.w += et*x.w;
  }
  float m = smx;
  float* out = zbuf + (size_t)b*VC + v0;
  out[0] = __logf(acc.x) + m;
  out[1] = __logf(acc.y) + m;
  out[2] = __logf(acc.z) + m;
  out[3] = __logf(acc.w) + m;
}

// ---------------------------------------------------------------------------
// Final softmax (3-pass, R8 version).
// ---------------------------------------------------------------------------
__global__ __launch_bounds__(256) void final_softmax2(
    const float* __restrict__ p0, const float* __restrict__ p1, const float* __restrict__ p2,
    const float* __restrict__ bias, const float* __restrict__ zbuf, float* __restrict__ out0)
{
  const int b = blockIdx.x, tid = threadIdx.x;
  const float* q0 = p0 + (size_t)b*V_;
  const float* q1 = p1 + (size_t)b*V_;
  const float* q2 = p2 + (size_t)b*V_;
  const float* zr = zbuf + (size_t)b*VC;
  __shared__ float sa[256];
  float mx = -INFINITY;
  for (int i = tid; i < V_; i += 256) mx = fmaxf(mx, q0[i]+q1[i]+q2[i]+bias[i]);
  for (int i = tid; i < VC; i += 256) mx = fmaxf(mx, zr[i]);
  sa[tid] = mx; __syncthreads();
  for (int o = 128; o > 0; o >>= 1) { if (tid < o) sa[tid] = fmaxf(sa[tid], sa[tid+o]); __syncthreads(); }
  mx = sa[0]; __syncthreads();
  float sum = 0.f;
  for (int i = tid; i < V_; i += 256) sum += __expf(q0[i]+q1[i]+q2[i]+bias[i] - mx);
  for (int i = tid; i < VC; i += 256) sum += __expf(zr[i] - mx);
  sa[tid] = sum; __syncthreads();
  for (int o = 128; o > 0; o >>= 1) { if (tid < o) sa[tid] += sa[tid+o]; __syncthreads(); }
  float inv = 1.f / sa[0];
  float* o0 = out0 + (size_t)b*VC;
  for (int j = tid; j < V_; j += 256)
    o0[j] = (__expf(q0[j]+q1[j]+q2[j]+bias[j]-mx) + __expf(zr[j]-mx)) * inv;
  for (int j = tid; j < TZ; j += 256)
    o0[V_ + j] = __expf(zr[V_ + j] - mx) * inv;
}

// ---------------------------------------------------------------------------
extern "C" void kernel_launch(void* const* d_in, const int* in_sizes, int n_in,
                              void* d_out, int out_size, void* d_ws, size_t ws_size,
                              hipStream_t stream)
{
  const float* z_enc   = (const float*)d_in[0];
  const float* u_enc   = (const float*)d_in[1];
  const int*   m_t     = (const int*)  d_in[2];
  const float* degree  = (const float*)d_in[3];
  const float* hidden  = (const float*)d_in[4];
  const float* sr      = (const float*)d_in[5];
  const float* emb     = (const float*)d_in[6];
  const float* attn_z_W= (const float*)d_in[7];
  const float* attn_z_b= (const float*)d_in[8];
  const float* attn_z_v= (const float*)d_in[9];
  const float* attn_u_W= (const float*)d_in[10];
  const float* attn_u_b= (const float*)d_in[11];
  const float* attn_u_v= (const float*)d_in[12];
  const float* gru_W_ih= (const float*)d_in[13];
  const float* gru_W_hh= (const float*)d_in[14];
  const float* gru_b_ih= (const float*)d_in[15];
  const float* gru_b_hh= (const float*)d_in[16];
  const float* proj_W  = (const float*)d_in[17];
  const float* proj_b  = (const float*)d_in[18];
  const float* copy2_W = (const float*)d_in[19];
  const float* copy2_b = (const float*)d_in[20];

  float* out0 = (float*)d_out;
  float* out1 = out0 + (size_t)B_*VC;
  float* out2 = out1 + (size_t)B_*H_;

  // Workspace — fp32 region
  float* ws    = (float*)d_ws;
  float* hWz   = ws;
  float* hWu   = hWz   + B_*H_;
  float* gh    = hWu   + B_*H_;
  float* partZ = gh    + B_*G3;
  float* partU = partZ + NB*B_*TZ;
  float* partC = partU + NB*B_*TU;
  float* giA   = partC + NB*B_*TZ;
  float* giB   = giA   + B_*G3;
  float* hnew  = giB   + B_*G3;
  float* p0    = hnew  + B_*H_;
  float* p1    = p0    + (size_t)B_*V_;
  float* p2    = p1    + (size_t)B_*V_;
  float* zbuf  = p2    + (size_t)B_*V_;
  // bf16 region
  __bf16* gin   = (__bf16*)(zbuf + (size_t)B_*VC);
  __bf16* Wp    = gin   + (size_t)B_*GINP;
  __bf16* zb    = Wp    + (size_t)G3*GINP;
  __bf16* ub    = zb    + (size_t)TZ*B_*H_;
  __bf16* hb    = ub    + (size_t)TU*B_*H_;
  __bf16* zWb   = hb    + (size_t)B_*H_;
  __bf16* uWb   = zWb   + (size_t)H_*2*H_;
  __bf16* cWb   = uWb   + (size_t)H_*2*H_;
  __bf16* whhb  = cWb   + (size_t)H_*H_;
  __bf16* pWb   = whhb  + (size_t)G3*H_;
  __bf16* cat3b = pWb   + (size_t)V_*G3;

  // 1. convert everything to bf16 (incl. proj_W and padded gru_W_ih)
  cvt_all<<<(CVT_UNITS + 255)/256, 256, 0, stream>>>(
      z_enc, u_enc, hidden, attn_z_W, attn_u_W, copy2_W, gru_W_hh, proj_W, gru_W_ih,
      zb, ub, hb, zWb, uWb, cWb, whhb, pWb, Wp);

  // 2. fused hidden-side GEMMs
  hidden3<<<20, 256, 0, stream>>>(hb, zWb, attn_z_b, hWz, uWb, attn_u_b, hWu, whhb, gru_b_hh, gh);

  // 3. fused z+u attention energies (R8 structure: 3072 tiles)
  mfma_energy2<<<768, 256, 0, stream>>>(
      zb, zWb + H_, 2*H_, hWz, H_, attn_z_v, 0, partZ, TZ,
      ub, uWb + H_, 2*H_, hWu, H_, attn_u_v, 0, partU, TU,
      1024, 3072);

  // 4. fused softmax + context (vectorized) + concat
  attn_ctx_concat<<<B_, 256, 0, stream>>>(partZ, partU, zb, ub, m_t, emb, degree, gin, cat3b);

  // 5. GRU input GEMM (K-split x2) + pointwise
  mfma_gru<<<24, 256, 0, stream>>>(gin, Wp, giA, giB);
  gru_kernel<<<(B_*H_)/256, 256, 0, stream>>>(giA, giB, gh, gru_b_ih, hidden, hnew, cat3b, out1, out2);

  // 6. fused projection + copy-energy (1774 tiles)
  proj_copy<<<444, 256, 0, stream>>>(cat3b, pWb, p0, zb, cWb, copy2_b, hnew, partC);

  // 7. zcopy (zexp folded in)
  zcopy_kernel<<<dim3((VC + 1023)/1024, B_), 256, 0, stream>>>(partC, sr, zbuf);

  // 8. final softmax + output assembly
  final_softmax2<<<B_, 256, 0, stream>>>(p0, p1, p2, proj_b, zbuf, out0);
}

// Round 13
// 295.916 us; speedup vs baseline: 1.1792x; 1.0044x over previous
//
#include <hip/hip_runtime.h>
#include <hip/hip_bf16.h>
#include <math.h>

// Problem constants
#define B_   128
#define H_   512
#define TZ   64
#define TU   128
#define V_   8000
#define VC   8064            // V + TZ
#define GIN  1541            // E + 2H + 5
#define GINP 1568            // GIN padded to multiple of 32
#define G3   1536            // 3*H
#define NB   8               // n-blocks per 512-wide energy GEMM

typedef float f32x4 __attribute__((ext_vector_type(4)));
typedef __bf16 bf16x8 __attribute__((ext_vector_type(8)));

__device__ __forceinline__ float sigmoidf_(float x){ return 1.f/(1.f+__expf(-x)); }

__device__ __forceinline__ bf16x8 load8_bf16(const float* __restrict__ p){
  float4 x = *(const float4*)p;
  float4 y = *(const float4*)(p+4);
  bf16x8 r;
  r[0]=(__bf16)x.x; r[1]=(__bf16)x.y; r[2]=(__bf16)x.z; r[3]=(__bf16)x.w;
  r[4]=(__bf16)y.x; r[5]=(__bf16)y.y; r[6]=(__bf16)y.z; r[7]=(__bf16)y.w;
  return r;
}
__device__ __forceinline__ void cvt8(const float* __restrict__ s, __bf16* __restrict__ d){
  *(bf16x8*)d = load8_bf16(s);
}

// ---------------------------------------------------------------------------
// Fused: hidden-side GEMMs (blocks 0..19, fp32-direct inputs) + one-pass
// fp32->bf16 conversion (blocks 20.., unit = 8 elems; gru_W_ih padded).
// hb/whhb no longer converted (hidden3 tiles read fp32 directly).
// ---------------------------------------------------------------------------
#define U_Z   524288u     // z_enc
#define U_U   1048576u    // u_enc
#define U_ZW  65536u      // attn_z_W
#define U_UW  65536u      // attn_u_W
#define U_CW  32768u      // copy2_W
#define U_PW  1536000u    // proj_W
#define U_WIH 301056u     // gru_W_ih padded: 1536*1568/8
#define CVT_UNITS (U_Z+U_U+U_ZW+U_UW+U_CW+U_PW+U_WIH)   // 3573760
#define GEMM_BLOCKS 20

__global__ __launch_bounds__(256) void cvt_hidden3(
    const float* __restrict__ z, const float* __restrict__ u, const float* __restrict__ hid,
    const float* __restrict__ zW, const float* __restrict__ uW, const float* __restrict__ cW,
    const float* __restrict__ whh, const float* __restrict__ pW, const float* __restrict__ wih,
    __bf16* __restrict__ zb, __bf16* __restrict__ ub,
    __bf16* __restrict__ zWb, __bf16* __restrict__ uWb, __bf16* __restrict__ cWb,
    __bf16* __restrict__ pWb, __bf16* __restrict__ Wp,
    const float* __restrict__ zbias, float* __restrict__ hWz,
    const float* __restrict__ ubias, float* __restrict__ hWu,
    const float* __restrict__ hbias, float* __restrict__ gh)
{
  if (blockIdx.x < GEMM_BLOCKS) {
    // ---- hidden-side GEMM tiles, fp32 operands converted in-register ----
    const int wv = threadIdx.x >> 6, lane = threadIdx.x & 63;
    const int tile = blockIdx.x*4 + wv;
    if (tile >= 80) return;
    const float* W; const float* bias; float* C; int ldw, ldc, nbn, lt;
    if (tile < 16)      { W=zW;  bias=zbias; C=hWz; ldw=2*H_; ldc=H_; nbn=8;  lt=tile; }
    else if (tile < 32) { W=uW;  bias=ubias; C=hWu; ldw=2*H_; ldc=H_; nbn=8;  lt=tile-16; }
    else                { W=whh; bias=hbias; C=gh;  ldw=H_;   ldc=G3; nbn=24; lt=tile-32; }
    const int bn = (lt % nbn) * 64, bm = (lt / nbn) * 64;
    const int col = lane & 15, g = lane >> 4;
    f32x4 acc[4][4] = {};
    for (int k0 = 0; k0 < 512; k0 += 32) {
      const int k = k0 + g*8;
      bf16x8 af[4], bw[4];
#pragma unroll
      for (int i = 0; i < 4; ++i) {
        af[i] = load8_bf16(hid + (size_t)(bm + i*16 + col)*H_ + k);
        bw[i] = load8_bf16(W   + (size_t)(bn + i*16 + col)*ldw + k);
      }
#pragma unroll
      for (int i = 0; i < 4; ++i)
#pragma unroll
        for (int j = 0; j < 4; ++j)
          acc[i][j] = __builtin_amdgcn_mfma_f32_16x16x32_bf16(af[i], bw[j], acc[i][j], 0, 0, 0);
    }
#pragma unroll
    for (int mi = 0; mi < 4; ++mi)
#pragma unroll
      for (int r = 0; r < 4; ++r) {
        int m = bm + mi*16 + g*4 + r;
#pragma unroll
        for (int ni = 0; ni < 4; ++ni) {
          int n = bn + ni*16 + col;
          C[(size_t)m*ldc + n] = acc[mi][ni][r] + bias[n];
        }
      }
    return;
  }
  // ---- conversion segment ----
  unsigned t = (blockIdx.x - GEMM_BLOCKS)*256u + threadIdx.x;
  if (t >= CVT_UNITS) return;
  unsigned o = t;
  if (o >= CVT_UNITS - U_WIH) {           // gru_W_ih pad segment (scalar loads)
    o -= (CVT_UNITS - U_WIH);
    unsigned r = o / (GINP/8), cu = o % (GINP/8);
    int c0 = cu*8;
    const float* src = wih + (size_t)r*GIN;
    bf16x8 v;
#pragma unroll
    for (int e = 0; e < 8; ++e) {
      int c = c0 + e;
      v[e] = (__bf16)((c < GIN) ? src[c] : 0.f);
    }
    *(bf16x8*)(Wp + (size_t)r*GINP + c0) = v;
    return;
  }
  const float* s; __bf16* d;
  if      (o < U_Z)                   { s=z;   d=zb;   }
  else if ((o-=U_Z)   < U_U)          { s=u;   d=ub;   }
  else if ((o-=U_U)   < U_ZW)         { s=zW;  d=zWb;  }
  else if ((o-=U_ZW)  < U_UW)         { s=uW;  d=uWb;  }
  else if ((o-=U_UW)  < U_CW)         { s=cW;  d=cWb;  }
  else     { o-=U_CW;                   s=pW;  d=pWb;  }
  cvt8(s + (size_t)o*8, d + (size_t)o*8);
}

// ---------------------------------------------------------------------------
// Fused z+u attention energies (bf16), R8 structure (acc[4][4], 3072 tiles).
//   partial[nb][b*T+t] = sum_{n in nb} tanh(acc + add[b*as+n]) * mul[b*ms+n]
// ---------------------------------------------------------------------------
__global__ __launch_bounds__(256) void mfma_energy2(
    const __bf16* __restrict__ Az, const __bf16* __restrict__ Wz, int ldwz,
    const float* __restrict__ addz, int asz, const float* __restrict__ mulz, int msz,
    float* __restrict__ outz, int Tz,
    const __bf16* __restrict__ Au, const __bf16* __restrict__ Wu, int ldwu,
    const float* __restrict__ addu, int asu, const float* __restrict__ mulu, int msu,
    float* __restrict__ outu, int Tu,
    int ztiles, int ntiles)
{
  const int wv = threadIdx.x >> 6, lane = threadIdx.x & 63;
  const int tile = blockIdx.x*4 + wv;
  if (tile >= ntiles) return;
  const __bf16 *A, *W; const float *add, *mul; float* outp;
  int ldw, as, ms, T, lt;
  if (tile < ztiles) { A=Az; W=Wz; ldw=ldwz; add=addz; as=asz; mul=mulz; ms=msz; outp=outz; T=Tz; lt=tile; }
  else               { A=Au; W=Wu; ldw=ldwu; add=addu; as=asu; mul=mulu; ms=msu; outp=outu; T=Tu; lt=tile-ztiles; }
  const int nb = lt & 7;
  const int bn = nb * 64, bm = (lt >> 3) * 64;
  const int col = lane & 15, g = lane >> 4;
  f32x4 acc[4][4] = {};
  for (int k0 = 0; k0 < 512; k0 += 32) {
    const int k = k0 + g*8;
    bf16x8 af[4], bw[4];
#pragma unroll
    for (int i = 0; i < 4; ++i) {
      af[i] = *(const bf16x8*)(A + (size_t)(bm + i*16 + col)*512 + k);
      bw[i] = *(const bf16x8*)(W + (size_t)(bn + i*16 + col)*ldw + k);
    }
#pragma unroll
    for (int i = 0; i < 4; ++i)
#pragma unroll
      for (int j = 0; j < 4; ++j)
        acc[i][j] = __builtin_amdgcn_mfma_f32_16x16x32_bf16(af[i], bw[j], acc[i][j], 0, 0, 0);
  }
#pragma unroll
  for (int mi = 0; mi < 4; ++mi)
#pragma unroll
    for (int r = 0; r < 4; ++r) {
      int m = bm + mi*16 + g*4 + r;
      int b = m & (B_-1), t = m >> 7;
      float p = 0.f;
#pragma unroll
      for (int ni = 0; ni < 4; ++ni) {
        int n = bn + ni*16 + col;
        float v = tanhf(acc[mi][ni][r] + add[(size_t)b*as + n]);
        p += v * mul[(size_t)b*ms + n];
      }
      p += __shfl_xor(p, 1); p += __shfl_xor(p, 2);
      p += __shfl_xor(p, 4); p += __shfl_xor(p, 8);
      if (col == 0) outp[(size_t)nb*(B_*T) + b*T + t] = p;
    }
}

// ---------------------------------------------------------------------------
// Fused: z+u softmax over partials + both contexts (bf16x8, all 4 waves) +
// concat into gin/cat3b. One block per batch row.
// ---------------------------------------------------------------------------
__global__ __launch_bounds__(256) void attn_ctx_concat(
    const float* __restrict__ partZ, const float* __restrict__ partU,
    const __bf16* __restrict__ zb, const __bf16* __restrict__ ub,
    const int* __restrict__ m_t, const float* __restrict__ emb,
    const float* __restrict__ degree,
    __bf16* __restrict__ gin, __bf16* __restrict__ cat3b)
{
  const int b = blockIdx.x, tid = threadIdx.x;
  __shared__ float sa[256];
  __shared__ float awz[TZ];
  __shared__ float awu[TU];
  __shared__ float szcA[H_], szcB[H_], sucA[H_], sucB[H_];
  {
    float s = -INFINITY;
    if (tid < TZ) {
      s = 0.f;
#pragma unroll
      for (int nb = 0; nb < NB; ++nb) s += partZ[(size_t)nb*(B_*TZ) + b*TZ + tid];
    }
    sa[tid] = s; __syncthreads();
    for (int o = 128; o > 0; o >>= 1) { if (tid < o) sa[tid] = fmaxf(sa[tid], sa[tid+o]); __syncthreads(); }
    float mx = sa[0]; __syncthreads();
    float e = (tid < TZ) ? __expf(s - mx) : 0.f;
    sa[tid] = e; __syncthreads();
    for (int o = 128; o > 0; o >>= 1) { if (tid < o) sa[tid] += sa[tid+o]; __syncthreads(); }
    float inv = 1.f / sa[0];
    if (tid < TZ) awz[tid] = e * inv;
    __syncthreads();
  }
  {
    float s = -INFINITY;
    if (tid < TU) {
      s = 0.f;
#pragma unroll
      for (int nb = 0; nb < NB; ++nb) s += partU[(size_t)nb*(B_*TU) + b*TU + tid];
    }
    sa[tid] = s; __syncthreads();
    for (int o = 128; o > 0; o >>= 1) { if (tid < o) sa[tid] = fmaxf(sa[tid], sa[tid+o]); __syncthreads(); }
    float mx = sa[0]; __syncthreads();
    float e = (tid < TU) ? __expf(s - mx) : 0.f;
    sa[tid] = e; __syncthreads();
    for (int o = 128; o > 0; o >>= 1) { if (tid < o) sa[tid] += sa[tid+o]; __syncthreads(); }
    float inv = 1.f / sa[0];
    if (tid < TU) awu[tid] = e * inv;
    __syncthreads();
  }
  // contexts: all 4 waves active. w0: z t[0,32)  w2: z t[32,64)
  //                               w1: u t[0,64)  w3: u t[64,128)
  {
    const int wvi = tid >> 6, l = tid & 63;
    const int h0 = l * 8;
    float a0=0,a1=0,a2=0,a3=0,a4=0,a5=0,a6=0,a7=0;
    const __bf16* src; const float* aw; int t0, t1; float* dst;
    if      (wvi == 0) { src=zb; aw=awz; t0=0;  t1=32;  dst=szcA; }
    else if (wvi == 2) { src=zb; aw=awz; t0=32; t1=64;  dst=szcB; }
    else if (wvi == 1) { src=ub; aw=awu; t0=0;  t1=64;  dst=sucA; }
    else               { src=ub; aw=awu; t0=64; t1=128; dst=sucB; }
    for (int t = t0; t < t1; ++t) {
      float w = aw[t];
      bf16x8 v = *(const bf16x8*)(src + ((size_t)t*B_ + b)*H_ + h0);
      a0 += w*(float)v[0]; a1 += w*(float)v[1]; a2 += w*(float)v[2]; a3 += w*(float)v[3];
      a4 += w*(float)v[4]; a5 += w*(float)v[5]; a6 += w*(float)v[6]; a7 += w*(float)v[7];
    }
    dst[h0+0]=a0; dst[h0+1]=a1; dst[h0+2]=a2; dst[h0+3]=a3;
    dst[h0+4]=a4; dst[h0+5]=a5; dst[h0+6]=a6; dst[h0+7]=a7;
  }
  __syncthreads();
  const float* e = emb + (size_t)m_t[b] * H_;
  for (int h = tid; h < H_; h += 256) {
    float accz = szcA[h] + szcB[h];
    float accu = sucA[h] + sucB[h];
    gin[(size_t)b*GINP + h]          = (__bf16)e[h];
    gin[(size_t)b*GINP + H_ + h]     = (__bf16)accu;
    gin[(size_t)b*GINP + 2*H_ + h]   = (__bf16)accz;
    cat3b[(size_t)b*G3 + h]          = (__bf16)accz;
    cat3b[(size_t)b*G3 + H_ + h]     = (__bf16)accu;
  }
  if (tid < 5) gin[(size_t)b*GINP + 3*H_ + tid] = (__bf16)degree[b*5 + tid];
  if (tid >= 5 && tid < 32) gin[(size_t)b*GINP + GIN + (tid-5)] = (__bf16)0.f;
}

// ---------------------------------------------------------------------------
// GRU input GEMM, K-split x2.
// ---------------------------------------------------------------------------
__global__ __launch_bounds__(256) void mfma_gru(
    const __bf16* __restrict__ A, const __bf16* __restrict__ W,
    float* __restrict__ giA, float* __restrict__ giB)
{
  const int wv = threadIdx.x >> 6, lane = threadIdx.x & 63;
  const int tile = blockIdx.x*4 + wv;
  if (tile >= 96) return;
  const int half = tile / 48, lt = tile % 48;
  const int bn = (lt % 24) * 64, bm = (lt / 24) * 64;
  const int col = lane & 15, g = lane >> 4;
  const int kbeg = half ? 800 : 0, kend_ = half ? GINP : 800;
  float* C = half ? giB : giA;
  f32x4 acc[4][4] = {};
  for (int k0 = kbeg; k0 < kend_; k0 += 32) {
    const int k = k0 + g*8;
    bf16x8 af[4], bw[4];
#pragma unroll
    for (int i = 0; i < 4; ++i) {
      af[i] = *(const bf16x8*)(A + (size_t)(bm + i*16 + col)*GINP + k);
      bw[i] = *(const bf16x8*)(W + (size_t)(bn + i*16 + col)*GINP + k);
    }
#pragma unroll
    for (int i = 0; i < 4; ++i)
#pragma unroll
      for (int j = 0; j < 4; ++j)
        acc[i][j] = __builtin_amdgcn_mfma_f32_16x16x32_bf16(af[i], bw[j], acc[i][j], 0, 0, 0);
  }
#pragma unroll
  for (int mi = 0; mi < 4; ++mi)
#pragma unroll
    for (int r = 0; r < 4; ++r) {
      int m = bm + mi*16 + g*4 + r;
#pragma unroll
      for (int ni = 0; ni < 4; ++ni)
        C[(size_t)m*G3 + bn + ni*16 + col] = acc[mi][ni][r];
    }
}

// ---------------------------------------------------------------------------
// GRU pointwise.
// ---------------------------------------------------------------------------
__global__ __launch_bounds__(256) void gru_kernel(
    const float* __restrict__ giA, const float* __restrict__ giB,
    const float* __restrict__ gh, const float* __restrict__ bih,
    const float* __restrict__ hprev,
    float* __restrict__ hnew, __bf16* __restrict__ cat3b,
    float* __restrict__ out1, float* __restrict__ out2)
{
  int idx = blockIdx.x*256 + threadIdx.x;        // B*H
  int b = idx >> 9, h = idx & (H_-1);
  size_t base = (size_t)b*G3;
  float ir = giA[base + h]        + giB[base + h]        + bih[h]        + gh[base + h];
  float iz = giA[base + H_ + h]   + giB[base + H_ + h]   + bih[H_ + h]   + gh[base + H_ + h];
  float in_= giA[base + 2*H_ + h] + giB[base + 2*H_ + h] + bih[2*H_ + h];
  float hn = gh[base + 2*H_ + h];
  float r = sigmoidf_(ir);
  float z = sigmoidf_(iz);
  float n = tanhf(in_ + r*hn);
  float hv = (1.f - z)*n + z*hprev[idx];
  hnew[idx] = hv;
  cat3b[base + 2*H_ + h] = (__bf16)hv;
  out1[idx] = hv;
  out2[idx] = hv;
}

// ---------------------------------------------------------------------------
// Fused projection (K-split x3, bf16 W, 750 tiles) + copy-energy (1024 tiles).
// ---------------------------------------------------------------------------
__global__ __launch_bounds__(256) void proj_copy(
    const __bf16* __restrict__ cat3b, const __bf16* __restrict__ pWb, float* __restrict__ P,
    const __bf16* __restrict__ zb, const __bf16* __restrict__ cWb,
    const float* __restrict__ c2b, const float* __restrict__ hnew,
    float* __restrict__ partC)
{
  const int wv = threadIdx.x >> 6, lane = threadIdx.x & 63;
  const int tile = blockIdx.x*4 + wv;
  const int col = lane & 15, g = lane >> 4;
  if (tile < 750) {
    const int s = tile / 250, t2 = tile % 250;
    const int bn = (t2 % 125) * 64, bm = (t2 / 125) * 64;
    const __bf16* As = cat3b + s*512;
    const __bf16* Ws = pWb + s*512;
    float* C = P + (size_t)s*B_*V_;
    f32x4 acc[4][4] = {};
    for (int k0 = 0; k0 < 512; k0 += 32) {
      const int k = k0 + g*8;
      bf16x8 af[4], bw[4];
#pragma unroll
      for (int i = 0; i < 4; ++i) {
        af[i] = *(const bf16x8*)(As + (size_t)(bm + i*16 + col)*G3 + k);
        bw[i] = *(const bf16x8*)(Ws + (size_t)(bn + i*16 + col)*G3 + k);
      }
#pragma unroll
      for (int i = 0; i < 4; ++i)
#pragma unroll
        for (int j = 0; j < 4; ++j)
          acc[i][j] = __builtin_amdgcn_mfma_f32_16x16x32_bf16(af[i], bw[j], acc[i][j], 0, 0, 0);
    }
#pragma unroll
    for (int mi = 0; mi < 4; ++mi)
#pragma unroll
      for (int r = 0; r < 4; ++r) {
        int m = bm + mi*16 + g*4 + r;
#pragma unroll
        for (int ni = 0; ni < 4; ++ni)
          C[(size_t)m*V_ + bn + ni*16 + col] = acc[mi][ni][r];
      }
  } else if (tile < 750 + 1024) {
    const int lt = tile - 750;
    const int nb = lt & 7;
    const int bn = nb * 64, bm = (lt >> 3) * 64;
    f32x4 acc[4][4] = {};
    for (int k0 = 0; k0 < 512; k0 += 32) {
      const int k = k0 + g*8;
      bf16x8 af[4], bw[4];
#pragma unroll
      for (int i = 0; i < 4; ++i) {
        af[i] = *(const bf16x8*)(zb + (size_t)(bm + i*16 + col)*512 + k);
        bw[i] = *(const bf16x8*)(cWb + (size_t)(bn + i*16 + col)*H_ + k);
      }
#pragma unroll
      for (int i = 0; i < 4; ++i)
#pragma unroll
        for (int j = 0; j < 4; ++j)
          acc[i][j] = __builtin_amdgcn_mfma_f32_16x16x32_bf16(af[i], bw[j], acc[i][j], 0, 0, 0);
    }
#pragma unroll
    for (int mi = 0; mi < 4; ++mi)
#pragma unroll
      for (int r = 0; r < 4; ++r) {
        int m = bm + mi*16 + g*4 + r;
        int b = m & (B_-1), t = m >> 7;
        float p = 0.f;
#pragma unroll
        for (int ni = 0; ni < 4; ++ni) {
          int n = bn + ni*16 + col;
          float v = tanhf(acc[mi][ni][r] + c2b[n]);
          p += v * hnew[(size_t)b*H_ + n];
        }
        p += __shfl_xor(p, 1); p += __shfl_xor(p, 2);
        p += __shfl_xor(p, 4); p += __shfl_xor(p, 8);
        if (col == 0) partC[(size_t)nb*(B_*TZ) + b*TZ + t] = p;
      }
  }
}

// ---------------------------------------------------------------------------
// zcopy with folded zexp.
// ---------------------------------------------------------------------------
__global__ __launch_bounds__(256) void zcopy_kernel(
    const float* __restrict__ partC, const float* __restrict__ sr,
    float* __restrict__ zbuf)
{
  const int b = blockIdx.y, tid = threadIdx.x;
  __shared__ float se[TZ];
  __shared__ float smx;
  if (tid < TZ) {
    float s = 0.f;
#pragma unroll
    for (int nb = 0; nb < NB; ++nb) s += partC[(size_t)nb*(B_*TZ) + b*TZ + tid];
    float mx = s;
    mx = fmaxf(mx, __shfl_xor(mx, 1));  mx = fmaxf(mx, __shfl_xor(mx, 2));
    mx = fmaxf(mx, __shfl_xor(mx, 4));  mx = fmaxf(mx, __shfl_xor(mx, 8));
    mx = fmaxf(mx, __shfl_xor(mx, 16)); mx = fmaxf(mx, __shfl_xor(mx, 32));
    se[tid] = __expf(s - mx);
    if (tid == 0) smx = mx;
  }
  __syncthreads();
  const int v0 = blockIdx.x*1024 + tid*4;
  if (v0 >= VC) return;
  float4 acc = {0.f, 0.f, 0.f, 0.f};
  const float* base = sr + (size_t)b*TZ*VC;
#pragma unroll 4
  for (int t = 0; t < TZ; ++t) {
    float et = se[t];
    float4 x = *(const float4*)(base + (size_t)t*VC + v0);
    acc.x += et*x.x; acc.y += et*x.y; acc.z += et*x.z; acc.w += et*x.w;
  }
  float m = smx;
  float* out = zbuf + (size_t)b*VC + v0;
  out[0] = __logf(acc.x) + m;
  out[1] = __logf(acc.y) + m;
  out[2] = __logf(acc.z) + m;
  out[3] = __logf(acc.w) + m;
}

// ---------------------------------------------------------------------------
// Final softmax (3-pass).
// ---------------------------------------------------------------------------
__global__ __launch_bounds__(256) void final_softmax2(
    const float* __restrict__ p0, const float* __restrict__ p1, const float* __restrict__ p2,
    const float* __restrict__ bias, const float* __restrict__ zbuf, float* __restrict__ out0)
{
  const int b = blockIdx.x, tid = threadIdx.x;
  const float* q0 = p0 + (size_t)b*V_;
  const float* q1 = p1 + (size_t)b*V_;
  const float* q2 = p2 + (size_t)b*V_;
  const float* zr = zbuf + (size_t)b*VC;
  __shared__ float sa[256];
  float mx = -INFINITY;
  for (int i = tid; i < V_; i += 256) mx = fmaxf(mx, q0[i]+q1[i]+q2[i]+bias[i]);
  for (int i = tid; i < VC; i += 256) mx = fmaxf(mx, zr[i]);
  sa[tid] = mx; __syncthreads();
  for (int o = 128; o > 0; o >>= 1) { if (tid < o) sa[tid] = fmaxf(sa[tid], sa[tid+o]); __syncthreads(); }
  mx = sa[0]; __syncthreads();
  float sum = 0.f;
  for (int i = tid; i < V_; i += 256) sum += __expf(q0[i]+q1[i]+q2[i]+bias[i] - mx);
  for (int i = tid; i < VC; i += 256) sum += __expf(zr[i] - mx);
  sa[tid] = sum; __syncthreads();
  for (int o = 128; o > 0; o >>= 1) { if (tid < o) sa[tid] += sa[tid+o]; __syncthreads(); }
  float inv = 1.f / sa[0];
  float* o0 = out0 + (size_t)b*VC;
  for (int j = tid; j < V_; j += 256)
    o0[j] = (__expf(q0[j]+q1[j]+q2[j]+bias[j]-mx) + __expf(zr[j]-mx)) * inv;
  for (int j = tid; j < TZ; j += 256)
    o0[V_ + j] = __expf(zr[V_ + j] - mx) * inv;
}

// ---------------------------------------------------------------------------
extern "C" void kernel_launch(void* const* d_in, const int* in_sizes, int n_in,
                              void* d_out, int out_size, void* d_ws, size_t ws_size,
                              hipStream_t stream)
{
  const float* z_enc   = (const float*)d_in[0];
  const float* u_enc   = (const float*)d_in[1];
  const int*   m_t     = (const int*)  d_in[2];
  const float* degree  = (const float*)d_in[3];
  const float* hidden  = (const float*)d_in[4];
  const float* sr      = (const float*)d_in[5];
  const float* emb     = (const float*)d_in[6];
  const float* attn_z_W= (const float*)d_in[7];
  const float* attn_z_b= (const float*)d_in[8];
  const float* attn_z_v= (const float*)d_in[9];
  const float* attn_u_W= (const float*)d_in[10];
  const float* attn_u_b= (const float*)d_in[11];
  const float* attn_u_v= (const float*)d_in[12];
  const float* gru_W_ih= (const float*)d_in[13];
  const float* gru_W_hh= (const float*)d_in[14];
  const float* gru_b_ih= (const float*)d_in[15];
  const float* gru_b_hh= (const float*)d_in[16];
  const float* proj_W  = (const float*)d_in[17];
  const float* proj_b  = (const float*)d_in[18];
  const float* copy2_W = (const float*)d_in[19];
  const float* copy2_b = (const float*)d_in[20];

  float* out0 = (float*)d_out;
  float* out1 = out0 + (size_t)B_*VC;
  float* out2 = out1 + (size_t)B_*H_;

  // Workspace — fp32 region
  float* ws    = (float*)d_ws;
  float* hWz   = ws;
  float* hWu   = hWz   + B_*H_;
  float* gh    = hWu   + B_*H_;
  float* partZ = gh    + B_*G3;
  float* partU = partZ + NB*B_*TZ;
  float* partC = partU + NB*B_*TU;
  float* giA   = partC + NB*B_*TZ;
  float* giB   = giA   + B_*G3;
  float* hnew  = giB   + B_*G3;
  float* p0    = hnew  + B_*H_;
  float* p1    = p0    + (size_t)B_*V_;
  float* p2    = p1    + (size_t)B_*V_;
  float* zbuf  = p2    + (size_t)B_*V_;
  // bf16 region
  __bf16* gin   = (__bf16*)(zbuf + (size_t)B_*VC);
  __bf16* Wp    = gin   + (size_t)B_*GINP;
  __bf16* zb    = Wp    + (size_t)G3*GINP;
  __bf16* ub    = zb    + (size_t)TZ*B_*H_;
  __bf16* zWb   = ub    + (size_t)TU*B_*H_;
  __bf16* uWb   = zWb   + (size_t)H_*2*H_;
  __bf16* cWb   = uWb   + (size_t)H_*2*H_;
  __bf16* pWb   = cWb   + (size_t)H_*H_;
  __bf16* cat3b = pWb   + (size_t)V_*G3;

  // 1. fused: hidden-side GEMMs (fp32-direct, blocks 0..19) + bf16 conversion
  cvt_hidden3<<<GEMM_BLOCKS + (CVT_UNITS + 255)/256, 256, 0, stream>>>(
      z_enc, u_enc, hidden, attn_z_W, attn_u_W, copy2_W, gru_W_hh, proj_W, gru_W_ih,
      zb, ub, zWb, uWb, cWb, pWb, Wp,
      attn_z_b, hWz, attn_u_b, hWu, gru_b_hh, gh);

  // 2. fused z+u attention energies (R8 structure: 3072 tiles)
  mfma_energy2<<<768, 256, 0, stream>>>(
      zb, zWb + H_, 2*H_, hWz, H_, attn_z_v, 0, partZ, TZ,
      ub, uWb + H_, 2*H_, hWu, H_, attn_u_v, 0, partU, TU,
      1024, 3072);

  // 3. fused softmax + context (4-wave split) + concat
  attn_ctx_concat<<<B_, 256, 0, stream>>>(partZ, partU, zb, ub, m_t, emb, degree, gin, cat3b);

  // 4. GRU input GEMM (K-split x2) + pointwise
  mfma_gru<<<24, 256, 0, stream>>>(gin, Wp, giA, giB);
  gru_kernel<<<(B_*H_)/256, 256, 0, stream>>>(giA, giB, gh, gru_b_ih, hidden, hnew, cat3b, out1, out2);

  // 5. fused projection + copy-energy (1774 tiles)
  proj_copy<<<444, 256, 0, stream>>>(cat3b, pWb, p0, zb, cWb, copy2_b, hnew, partC);

  // 6. zcopy (zexp folded in)
  zcopy_kernel<<<dim3((VC + 1023)/1024, B_), 256, 0, stream>>>(partC, sr, zbuf);

  // 7. final softmax + output assembly
  final_softmax2<<<B_, 256, 0, stream>>>(p0, p1, p2, proj_b, zbuf, out0);
}

// Round 14
// 292.631 us; speedup vs baseline: 1.1924x; 1.0112x over previous
//
#include <hip/hip_runtime.h>
#include <hip/hip_bf16.h>
#include <math.h>

// Problem constants
#define B_   128
#define H_   512
#define TZ   64
#define TU   128
#define V_   8000
#define VC   8064            // V + TZ
#define GIN  1541            // E + 2H + 5
#define GINP 1568            // GIN padded to multiple of 32
#define G3   1536            // 3*H
#define NB   8               // n-blocks per 512-wide energy GEMM

typedef float f32x4 __attribute__((ext_vector_type(4)));
typedef __bf16 bf16x8 __attribute__((ext_vector_type(8)));

__device__ __forceinline__ float sigmoidf_(float x){ return 1.f/(1.f+__expf(-x)); }

__device__ __forceinline__ bf16x8 load8_bf16(const float* __restrict__ p){
  float4 x = *(const float4*)p;
  float4 y = *(const float4*)(p+4);
  bf16x8 r;
  r[0]=(__bf16)x.x; r[1]=(__bf16)x.y; r[2]=(__bf16)x.z; r[3]=(__bf16)x.w;
  r[4]=(__bf16)y.x; r[5]=(__bf16)y.y; r[6]=(__bf16)y.z; r[7]=(__bf16)y.w;
  return r;
}
__device__ __forceinline__ void cvt8(const float* __restrict__ s, __bf16* __restrict__ d){
  *(bf16x8*)d = load8_bf16(s);
}

// ---------------------------------------------------------------------------
// Fused: hidden-side GEMMs (blocks 0..19, fp32-direct inputs) + one-pass
// fp32->bf16 conversion (blocks 20.., unit = 8 elems; gru_W_ih padded).
// ---------------------------------------------------------------------------
#define U_Z   524288u     // z_enc
#define U_U   1048576u    // u_enc
#define U_ZW  65536u      // attn_z_W
#define U_UW  65536u      // attn_u_W
#define U_CW  32768u      // copy2_W
#define U_PW  1536000u    // proj_W
#define U_WIH 301056u     // gru_W_ih padded: 1536*1568/8
#define CVT_UNITS (U_Z+U_U+U_ZW+U_UW+U_CW+U_PW+U_WIH)
#define GEMM_BLOCKS 20

__global__ __launch_bounds__(256) void cvt_hidden3(
    const float* __restrict__ z, const float* __restrict__ u, const float* __restrict__ hid,
    const float* __restrict__ zW, const float* __restrict__ uW, const float* __restrict__ cW,
    const float* __restrict__ whh, const float* __restrict__ pW, const float* __restrict__ wih,
    __bf16* __restrict__ zb, __bf16* __restrict__ ub,
    __bf16* __restrict__ zWb, __bf16* __restrict__ uWb, __bf16* __restrict__ cWb,
    __bf16* __restrict__ pWb, __bf16* __restrict__ Wp,
    const float* __restrict__ zbias, float* __restrict__ hWz,
    const float* __restrict__ ubias, float* __restrict__ hWu,
    const float* __restrict__ hbias, float* __restrict__ gh)
{
  if (blockIdx.x < GEMM_BLOCKS) {
    const int wv = threadIdx.x >> 6, lane = threadIdx.x & 63;
    const int tile = blockIdx.x*4 + wv;
    if (tile >= 80) return;
    const float* W; const float* bias; float* C; int ldw, ldc, nbn, lt;
    if (tile < 16)      { W=zW;  bias=zbias; C=hWz; ldw=2*H_; ldc=H_; nbn=8;  lt=tile; }
    else if (tile < 32) { W=uW;  bias=ubias; C=hWu; ldw=2*H_; ldc=H_; nbn=8;  lt=tile-16; }
    else                { W=whh; bias=hbias; C=gh;  ldw=H_;   ldc=G3; nbn=24; lt=tile-32; }
    const int bn = (lt % nbn) * 64, bm = (lt / nbn) * 64;
    const int col = lane & 15, g = lane >> 4;
    f32x4 acc[4][4] = {};
    for (int k0 = 0; k0 < 512; k0 += 32) {
      const int k = k0 + g*8;
      bf16x8 af[4], bw[4];
#pragma unroll
      for (int i = 0; i < 4; ++i) {
        af[i] = load8_bf16(hid + (size_t)(bm + i*16 + col)*H_ + k);
        bw[i] = load8_bf16(W   + (size_t)(bn + i*16 + col)*ldw + k);
      }
#pragma unroll
      for (int i = 0; i < 4; ++i)
#pragma unroll
        for (int j = 0; j < 4; ++j)
          acc[i][j] = __builtin_amdgcn_mfma_f32_16x16x32_bf16(af[i], bw[j], acc[i][j], 0, 0, 0);
    }
#pragma unroll
    for (int mi = 0; mi < 4; ++mi)
#pragma unroll
      for (int r = 0; r < 4; ++r) {
        int m = bm + mi*16 + g*4 + r;
#pragma unroll
        for (int ni = 0; ni < 4; ++ni) {
          int n = bn + ni*16 + col;
          C[(size_t)m*ldc + n] = acc[mi][ni][r] + bias[n];
        }
      }
    return;
  }
  unsigned t = (blockIdx.x - GEMM_BLOCKS)*256u + threadIdx.x;
  if (t >= CVT_UNITS) return;
  unsigned o = t;
  if (o >= CVT_UNITS - U_WIH) {           // gru_W_ih pad segment
    o -= (CVT_UNITS - U_WIH);
    unsigned r = o / (GINP/8), cu = o % (GINP/8);
    int c0 = cu*8;
    const float* src = wih + (size_t)r*GIN;
    bf16x8 v;
#pragma unroll
    for (int e = 0; e < 8; ++e) {
      int c = c0 + e;
      v[e] = (__bf16)((c < GIN) ? src[c] : 0.f);
    }
    *(bf16x8*)(Wp + (size_t)r*GINP + c0) = v;
    return;
  }
  const float* s; __bf16* d;
  if      (o < U_Z)                   { s=z;   d=zb;   }
  else if ((o-=U_Z)   < U_U)          { s=u;   d=ub;   }
  else if ((o-=U_U)   < U_ZW)         { s=zW;  d=zWb;  }
  else if ((o-=U_ZW)  < U_UW)         { s=uW;  d=uWb;  }
  else if ((o-=U_UW)  < U_CW)         { s=cW;  d=cWb;  }
  else     { o-=U_CW;                   s=pW;  d=pWb;  }
  cvt8(s + (size_t)o*8, d + (size_t)o*8);
}

// ---------------------------------------------------------------------------
// Fused z+u attention energies (bf16), R8 structure (acc[4][4], 3072 tiles).
// ---------------------------------------------------------------------------
__global__ __launch_bounds__(256) void mfma_energy2(
    const __bf16* __restrict__ Az, const __bf16* __restrict__ Wz, int ldwz,
    const float* __restrict__ addz, int asz, const float* __restrict__ mulz, int msz,
    float* __restrict__ outz, int Tz,
    const __bf16* __restrict__ Au, const __bf16* __restrict__ Wu, int ldwu,
    const float* __restrict__ addu, int asu, const float* __restrict__ mulu, int msu,
    float* __restrict__ outu, int Tu,
    int ztiles, int ntiles)
{
  const int wv = threadIdx.x >> 6, lane = threadIdx.x & 63;
  const int tile = blockIdx.x*4 + wv;
  if (tile >= ntiles) return;
  const __bf16 *A, *W; const float *add, *mul; float* outp;
  int ldw, as, ms, T, lt;
  if (tile < ztiles) { A=Az; W=Wz; ldw=ldwz; add=addz; as=asz; mul=mulz; ms=msz; outp=outz; T=Tz; lt=tile; }
  else               { A=Au; W=Wu; ldw=ldwu; add=addu; as=asu; mul=mulu; ms=msu; outp=outu; T=Tu; lt=tile-ztiles; }
  const int nb = lt & 7;
  const int bn = nb * 64, bm = (lt >> 3) * 64;
  const int col = lane & 15, g = lane >> 4;
  f32x4 acc[4][4] = {};
  for (int k0 = 0; k0 < 512; k0 += 32) {
    const int k = k0 + g*8;
    bf16x8 af[4], bw[4];
#pragma unroll
    for (int i = 0; i < 4; ++i) {
      af[i] = *(const bf16x8*)(A + (size_t)(bm + i*16 + col)*512 + k);
      bw[i] = *(const bf16x8*)(W + (size_t)(bn + i*16 + col)*ldw + k);
    }
#pragma unroll
    for (int i = 0; i < 4; ++i)
#pragma unroll
      for (int j = 0; j < 4; ++j)
        acc[i][j] = __builtin_amdgcn_mfma_f32_16x16x32_bf16(af[i], bw[j], acc[i][j], 0, 0, 0);
  }
#pragma unroll
  for (int mi = 0; mi < 4; ++mi)
#pragma unroll
    for (int r = 0; r < 4; ++r) {
      int m = bm + mi*16 + g*4 + r;
      int b = m & (B_-1), t = m >> 7;
      float p = 0.f;
#pragma unroll
      for (int ni = 0; ni < 4; ++ni) {
        int n = bn + ni*16 + col;
        float v = tanhf(acc[mi][ni][r] + add[(size_t)b*as + n]);
        p += v * mul[(size_t)b*ms + n];
      }
      p += __shfl_xor(p, 1); p += __shfl_xor(p, 2);
      p += __shfl_xor(p, 4); p += __shfl_xor(p, 8);
      if (col == 0) outp[(size_t)nb*(B_*T) + b*T + t] = p;
    }
}

// ---------------------------------------------------------------------------
// Fused: z+u softmax over partials + both contexts (bf16x8, 4 waves) + concat.
// ---------------------------------------------------------------------------
__global__ __launch_bounds__(256) void attn_ctx_concat(
    const float* __restrict__ partZ, const float* __restrict__ partU,
    const __bf16* __restrict__ zb, const __bf16* __restrict__ ub,
    const int* __restrict__ m_t, const float* __restrict__ emb,
    const float* __restrict__ degree,
    __bf16* __restrict__ gin, __bf16* __restrict__ cat3b)
{
  const int b = blockIdx.x, tid = threadIdx.x;
  __shared__ float sa[256];
  __shared__ float awz[TZ];
  __shared__ float awu[TU];
  __shared__ float szcA[H_], szcB[H_], sucA[H_], sucB[H_];
  {
    float s = -INFINITY;
    if (tid < TZ) {
      s = 0.f;
#pragma unroll
      for (int nb = 0; nb < NB; ++nb) s += partZ[(size_t)nb*(B_*TZ) + b*TZ + tid];
    }
    sa[tid] = s; __syncthreads();
    for (int o = 128; o > 0; o >>= 1) { if (tid < o) sa[tid] = fmaxf(sa[tid], sa[tid+o]); __syncthreads(); }
    float mx = sa[0]; __syncthreads();
    float e = (tid < TZ) ? __expf(s - mx) : 0.f;
    sa[tid] = e; __syncthreads();
    for (int o = 128; o > 0; o >>= 1) { if (tid < o) sa[tid] += sa[tid+o]; __syncthreads(); }
    float inv = 1.f / sa[0];
    if (tid < TZ) awz[tid] = e * inv;
    __syncthreads();
  }
  {
    float s = -INFINITY;
    if (tid < TU) {
      s = 0.f;
#pragma unroll
      for (int nb = 0; nb < NB; ++nb) s += partU[(size_t)nb*(B_*TU) + b*TU + tid];
    }
    sa[tid] = s; __syncthreads();
    for (int o = 128; o > 0; o >>= 1) { if (tid < o) sa[tid] = fmaxf(sa[tid], sa[tid+o]); __syncthreads(); }
    float mx = sa[0]; __syncthreads();
    float e = (tid < TU) ? __expf(s - mx) : 0.f;
    sa[tid] = e; __syncthreads();
    for (int o = 128; o > 0; o >>= 1) { if (tid < o) sa[tid] += sa[tid+o]; __syncthreads(); }
    float inv = 1.f / sa[0];
    if (tid < TU) awu[tid] = e * inv;
    __syncthreads();
  }
  {
    const int wvi = tid >> 6, l = tid & 63;
    const int h0 = l * 8;
    float a0=0,a1=0,a2=0,a3=0,a4=0,a5=0,a6=0,a7=0;
    const __bf16* src; const float* aw; int t0, t1; float* dst;
    if      (wvi == 0) { src=zb; aw=awz; t0=0;  t1=32;  dst=szcA; }
    else if (wvi == 2) { src=zb; aw=awz; t0=32; t1=64;  dst=szcB; }
    else if (wvi == 1) { src=ub; aw=awu; t0=0;  t1=64;  dst=sucA; }
    else               { src=ub; aw=awu; t0=64; t1=128; dst=sucB; }
    for (int t = t0; t < t1; ++t) {
      float w = aw[t];
      bf16x8 v = *(const bf16x8*)(src + ((size_t)t*B_ + b)*H_ + h0);
      a0 += w*(float)v[0]; a1 += w*(float)v[1]; a2 += w*(float)v[2]; a3 += w*(float)v[3];
      a4 += w*(float)v[4]; a5 += w*(float)v[5]; a6 += w*(float)v[6]; a7 += w*(float)v[7];
    }
    dst[h0+0]=a0; dst[h0+1]=a1; dst[h0+2]=a2; dst[h0+3]=a3;
    dst[h0+4]=a4; dst[h0+5]=a5; dst[h0+6]=a6; dst[h0+7]=a7;
  }
  __syncthreads();
  const float* e = emb + (size_t)m_t[b] * H_;
  for (int h = tid; h < H_; h += 256) {
    float accz = szcA[h] + szcB[h];
    float accu = sucA[h] + sucB[h];
    gin[(size_t)b*GINP + h]          = (__bf16)e[h];
    gin[(size_t)b*GINP + H_ + h]     = (__bf16)accu;
    gin[(size_t)b*GINP + 2*H_ + h]   = (__bf16)accz;
    cat3b[(size_t)b*G3 + h]          = (__bf16)accz;
    cat3b[(size_t)b*G3 + H_ + h]     = (__bf16)accu;
  }
  if (tid < 5) gin[(size_t)b*GINP + 3*H_ + tid] = (__bf16)degree[b*5 + tid];
  if (tid >= 5 && tid < 32) gin[(size_t)b*GINP + GIN + (tid-5)] = (__bf16)0.f;
}

// ---------------------------------------------------------------------------
// GRU input GEMM, K-split x4 (segments {0,384,768,1184,1568}; 192 tiles, 48 blocks).
// ---------------------------------------------------------------------------
__global__ __launch_bounds__(256) void mfma_gru(
    const __bf16* __restrict__ A, const __bf16* __restrict__ W,
    float* __restrict__ gi)              // 4 x [128][1536]
{
  const int wv = threadIdx.x >> 6, lane = threadIdx.x & 63;
  const int tile = blockIdx.x*4 + wv;
  if (tile >= 192) return;
  const int seg = tile / 48, lt = tile % 48;
  const int bn = (lt % 24) * 64, bm = (lt / 24) * 64;
  const int col = lane & 15, g = lane >> 4;
  const int kb[5] = {0, 384, 768, 1184, GINP};
  const int kbeg = kb[seg], kend_ = kb[seg+1];
  float* C = gi + (size_t)seg*B_*G3;
  f32x4 acc[4][4] = {};
  for (int k0 = kbeg; k0 < kend_; k0 += 32) {
    const int k = k0 + g*8;
    bf16x8 af[4], bw[4];
#pragma unroll
    for (int i = 0; i < 4; ++i) {
      af[i] = *(const bf16x8*)(A + (size_t)(bm + i*16 + col)*GINP + k);
      bw[i] = *(const bf16x8*)(W + (size_t)(bn + i*16 + col)*GINP + k);
    }
#pragma unroll
    for (int i = 0; i < 4; ++i)
#pragma unroll
      for (int j = 0; j < 4; ++j)
        acc[i][j] = __builtin_amdgcn_mfma_f32_16x16x32_bf16(af[i], bw[j], acc[i][j], 0, 0, 0);
  }
#pragma unroll
  for (int mi = 0; mi < 4; ++mi)
#pragma unroll
    for (int r = 0; r < 4; ++r) {
      int m = bm + mi*16 + g*4 + r;
#pragma unroll
      for (int ni = 0; ni < 4; ++ni)
        C[(size_t)m*G3 + bn + ni*16 + col] = acc[mi][ni][r];
    }
}

// ---------------------------------------------------------------------------
// GRU pointwise (sums 4 K-split partials).
// ---------------------------------------------------------------------------
__global__ __launch_bounds__(256) void gru_kernel(
    const float* __restrict__ gi, const float* __restrict__ gh,
    const float* __restrict__ bih, const float* __restrict__ hprev,
    float* __restrict__ hnew, __bf16* __restrict__ cat3b,
    float* __restrict__ out1, float* __restrict__ out2)
{
  int idx = blockIdx.x*256 + threadIdx.x;        // B*H
  int b = idx >> 9, h = idx & (H_-1);
  size_t base = (size_t)b*G3;
  const size_t SEG = (size_t)B_*G3;
  float ir = bih[h], iz = bih[H_ + h], in_ = bih[2*H_ + h];
#pragma unroll
  for (int s = 0; s < 4; ++s) {
    ir  += gi[s*SEG + base + h];
    iz  += gi[s*SEG + base + H_ + h];
    in_ += gi[s*SEG + base + 2*H_ + h];
  }
  ir += gh[base + h];
  iz += gh[base + H_ + h];
  float hn = gh[base + 2*H_ + h];
  float r = sigmoidf_(ir);
  float z = sigmoidf_(iz);
  float n = tanhf(in_ + r*hn);
  float hv = (1.f - z)*n + z*hprev[idx];
  hnew[idx] = hv;
  cat3b[base + 2*H_ + h] = (__bf16)hv;
  out1[idx] = hv;
  out2[idx] = hv;
}

// ---------------------------------------------------------------------------
// Fused projection (K-split x3, bf16 W, 750 tiles) + copy-energy (1024 tiles).
// ---------------------------------------------------------------------------
__global__ __launch_bounds__(256) void proj_copy(
    const __bf16* __restrict__ cat3b, const __bf16* __restrict__ pWb, float* __restrict__ P,
    const __bf16* __restrict__ zb, const __bf16* __restrict__ cWb,
    const float* __restrict__ c2b, const float* __restrict__ hnew,
    float* __restrict__ partC)
{
  const int wv = threadIdx.x >> 6, lane = threadIdx.x & 63;
  const int tile = blockIdx.x*4 + wv;
  const int col = lane & 15, g = lane >> 4;
  if (tile < 750) {
    const int s = tile / 250, t2 = tile % 250;
    const int bn = (t2 % 125) * 64, bm = (t2 / 125) * 64;
    const __bf16* As = cat3b + s*512;
    const __bf16* Ws = pWb + s*512;
    float* C = P + (size_t)s*B_*V_;
    f32x4 acc[4][4] = {};
    for (int k0 = 0; k0 < 512; k0 += 32) {
      const int k = k0 + g*8;
      bf16x8 af[4], bw[4];
#pragma unroll
      for (int i = 0; i < 4; ++i) {
        af[i] = *(const bf16x8*)(As + (size_t)(bm + i*16 + col)*G3 + k);
        bw[i] = *(const bf16x8*)(Ws + (size_t)(bn + i*16 + col)*G3 + k);
      }
#pragma unroll
      for (int i = 0; i < 4; ++i)
#pragma unroll
        for (int j = 0; j < 4; ++j)
          acc[i][j] = __builtin_amdgcn_mfma_f32_16x16x32_bf16(af[i], bw[j], acc[i][j], 0, 0, 0);
    }
#pragma unroll
    for (int mi = 0; mi < 4; ++mi)
#pragma unroll
      for (int r = 0; r < 4; ++r) {
        int m = bm + mi*16 + g*4 + r;
#pragma unroll
        for (int ni = 0; ni < 4; ++ni)
          C[(size_t)m*V_ + bn + ni*16 + col] = acc[mi][ni][r];
      }
  } else if (tile < 750 + 1024) {
    const int lt = tile - 750;
    const int nb = lt & 7;
    const int bn = nb * 64, bm = (lt >> 3) * 64;
    f32x4 acc[4][4] = {};
    for (int k0 = 0; k0 < 512; k0 += 32) {
      const int k = k0 + g*8;
      bf16x8 af[4], bw[4];
#pragma unroll
      for (int i = 0; i < 4; ++i) {
        af[i] = *(const bf16x8*)(zb + (size_t)(bm + i*16 + col)*512 + k);
        bw[i] = *(const bf16x8*)(cWb + (size_t)(bn + i*16 + col)*H_ + k);
      }
#pragma unroll
      for (int i = 0; i < 4; ++i)
#pragma unroll
        for (int j = 0; j < 4; ++j)
          acc[i][j] = __builtin_amdgcn_mfma_f32_16x16x32_bf16(af[i], bw[j], acc[i][j], 0, 0, 0);
    }
#pragma unroll
    for (int mi = 0; mi < 4; ++mi)
#pragma unroll
      for (int r = 0; r < 4; ++r) {
        int m = bm + mi*16 + g*4 + r;
        int b = m & (B_-1), t = m >> 7;
        float p = 0.f;
#pragma unroll
        for (int ni = 0; ni < 4; ++ni) {
          int n = bn + ni*16 + col;
          float v = tanhf(acc[mi][ni][r] + c2b[n]);
          p += v * hnew[(size_t)b*H_ + n];
        }
        p += __shfl_xor(p, 1); p += __shfl_xor(p, 2);
        p += __shfl_xor(p, 4); p += __shfl_xor(p, 8);
        if (col == 0) partC[(size_t)nb*(B_*TZ) + b*TZ + t] = p;
      }
  }
}

// ---------------------------------------------------------------------------
// zcopy with folded zexp.
// ---------------------------------------------------------------------------
__global__ __launch_bounds__(256) void zcopy_kernel(
    const float* __restrict__ partC, const float* __restrict__ sr,
    float* __restrict__ zbuf)
{
  const int b = blockIdx.y, tid = threadIdx.x;
  __shared__ float se[TZ];
  __shared__ float smx;
  if (tid < TZ) {
    float s = 0.f;
#pragma unroll
    for (int nb = 0; nb < NB; ++nb) s += partC[(size_t)nb*(B_*TZ) + b*TZ + tid];
    float mx = s;
    mx = fmaxf(mx, __shfl_xor(mx, 1));  mx = fmaxf(mx, __shfl_xor(mx, 2));
    mx = fmaxf(mx, __shfl_xor(mx, 4));  mx = fmaxf(mx, __shfl_xor(mx, 8));
    mx = fmaxf(mx, __shfl_xor(mx, 16)); mx = fmaxf(mx, __shfl_xor(mx, 32));
    se[tid] = __expf(s - mx);
    if (tid == 0) smx = mx;
  }
  __syncthreads();
  const int v0 = blockIdx.x*1024 + tid*4;
  if (v0 >= VC) return;
  float4 acc = {0.f, 0.f, 0.f, 0.f};
  const float* base = sr + (size_t)b*TZ*VC;
#pragma unroll 4
  for (int t = 0; t < TZ; ++t) {
    float et = se[t];
    float4 x = *(const float4*)(base + (size_t)t*VC + v0);
    acc.x += et*x.x; acc.y += et*x.y; acc.z += et*x.z; acc.w += et*x.w;
  }
  float m = smx;
  float* out = zbuf + (size_t)b*VC + v0;
  out[0] = __logf(acc.x) + m;
  out[1] = __logf(acc.y) + m;
  out[2] = __logf(acc.z) + m;
  out[3] = __logf(acc.w) + m;
}

// ---------------------------------------------------------------------------
// Final softmax (3-pass).
// ---------------------------------------------------------------------------
__global__ __launch_bounds__(256) void final_softmax2(
    const float* __restrict__ p0, const float* __restrict__ p1, const float* __restrict__ p2,
    const float* __restrict__ bias, const float* __restrict__ zbuf, float* __restrict__ out0)
{
  const int b = blockIdx.x, tid = threadIdx.x;
  const float* q0 = p0 + (size_t)b*V_;
  const float* q1 = p1 + (size_t)b*V_;
  const float* q2 = p2 + (size_t)b*V_;
  const float* zr = zbuf + (size_t)b*VC;
  __shared__ float sa[256];
  float mx = -INFINITY;
  for (int i = tid; i < V_; i += 256) mx = fmaxf(mx, q0[i]+q1[i]+q2[i]+bias[i]);
  for (int i = tid; i < VC; i += 256) mx = fmaxf(mx, zr[i]);
  sa[tid] = mx; __syncthreads();
  for (int o = 128; o > 0; o >>= 1) { if (tid < o) sa[tid] = fmaxf(sa[tid], sa[tid+o]); __syncthreads(); }
  mx = sa[0]; __syncthreads();
  float sum = 0.f;
  for (int i = tid; i < V_; i += 256) sum += __expf(q0[i]+q1[i]+q2[i]+bias[i] - mx);
  for (int i = tid; i < VC; i += 256) sum += __expf(zr[i] - mx);
  sa[tid] = sum; __syncthreads();
  for (int o = 128; o > 0; o >>= 1) { if (tid < o) sa[tid] += sa[tid+o]; __syncthreads(); }
  float inv = 1.f / sa[0];
  float* o0 = out0 + (size_t)b*VC;
  for (int j = tid; j < V_; j += 256)
    o0[j] = (__expf(q0[j]+q1[j]+q2[j]+bias[j]-mx) + __expf(zr[j]-mx)) * inv;
  for (int j = tid; j < TZ; j += 256)
    o0[V_ + j] = __expf(zr[V_ + j] - mx) * inv;
}

// ---------------------------------------------------------------------------
extern "C" void kernel_launch(void* const* d_in, const int* in_sizes, int n_in,
                              void* d_out, int out_size, void* d_ws, size_t ws_size,
                              hipStream_t stream)
{
  const float* z_enc   = (const float*)d_in[0];
  const float* u_enc   = (const float*)d_in[1];
  const int*   m_t     = (const int*)  d_in[2];
  const float* degree  = (const float*)d_in[3];
  const float* hidden  = (const float*)d_in[4];
  const float* sr      = (const float*)d_in[5];
  const float* emb     = (const float*)d_in[6];
  const float* attn_z_W= (const float*)d_in[7];
  const float* attn_z_b= (const float*)d_in[8];
  const float* attn_z_v= (const float*)d_in[9];
  const float* attn_u_W= (const float*)d_in[10];
  const float* attn_u_b= (const float*)d_in[11];
  const float* attn_u_v= (const float*)d_in[12];
  const float* gru_W_ih= (const float*)d_in[13];
  const float* gru_W_hh= (const float*)d_in[14];
  const float* gru_b_ih= (const float*)d_in[15];
  const float* gru_b_hh= (const float*)d_in[16];
  const float* proj_W  = (const float*)d_in[17];
  const float* proj_b  = (const float*)d_in[18];
  const float* copy2_W = (const float*)d_in[19];
  const float* copy2_b = (const float*)d_in[20];

  float* out0 = (float*)d_out;
  float* out1 = out0 + (size_t)B_*VC;
  float* out2 = out1 + (size_t)B_*H_;

  // Workspace — fp32 region
  float* ws    = (float*)d_ws;
  float* hWz   = ws;
  float* hWu   = hWz   + B_*H_;
  float* gh    = hWu   + B_*H_;
  float* partZ = gh    + B_*G3;
  float* partU = partZ + NB*B_*TZ;
  float* partC = partU + NB*B_*TU;
  float* gi    = partC + NB*B_*TZ;        // 4 x 128*1536
  float* hnew  = gi    + 4*(size_t)B_*G3;
  float* p0    = hnew  + B_*H_;
  float* p1    = p0    + (size_t)B_*V_;
  float* p2    = p1    + (size_t)B_*V_;
  float* zbuf  = p2    + (size_t)B_*V_;
  // bf16 region
  __bf16* gin   = (__bf16*)(zbuf + (size_t)B_*VC);
  __bf16* Wp    = gin   + (size_t)B_*GINP;
  __bf16* zb    = Wp    + (size_t)G3*GINP;
  __bf16* ub    = zb    + (size_t)TZ*B_*H_;
  __bf16* zWb   = ub    + (size_t)TU*B_*H_;
  __bf16* uWb   = zWb   + (size_t)H_*2*H_;
  __bf16* cWb   = uWb   + (size_t)H_*2*H_;
  __bf16* pWb   = cWb   + (size_t)H_*H_;
  __bf16* cat3b = pWb   + (size_t)V_*G3;

  // 1. fused: hidden-side GEMMs (fp32-direct) + bf16 conversion
  cvt_hidden3<<<GEMM_BLOCKS + (CVT_UNITS + 255)/256, 256, 0, stream>>>(
      z_enc, u_enc, hidden, attn_z_W, attn_u_W, copy2_W, gru_W_hh, proj_W, gru_W_ih,
      zb, ub, zWb, uWb, cWb, pWb, Wp,
      attn_z_b, hWz, attn_u_b, hWu, gru_b_hh, gh);

  // 2. fused z+u attention energies
  mfma_energy2<<<768, 256, 0, stream>>>(
      zb, zWb + H_, 2*H_, hWz, H_, attn_z_v, 0, partZ, TZ,
      ub, uWb + H_, 2*H_, hWu, H_, attn_u_v, 0, partU, TU,
      1024, 3072);

  // 3. fused softmax + context + concat
  attn_ctx_concat<<<B_, 256, 0, stream>>>(partZ, partU, zb, ub, m_t, emb, degree, gin, cat3b);

  // 4. GRU input GEMM (K-split x4, 48 blocks) + pointwise
  mfma_gru<<<48, 256, 0, stream>>>(gin, Wp, gi);
  gru_kernel<<<(B_*H_)/256, 256, 0, stream>>>(gi, gh, gru_b_ih, hidden, hnew, cat3b, out1, out2);

  // 5. fused projection + copy-energy
  proj_copy<<<444, 256, 0, stream>>>(cat3b, pWb, p0, zb, cWb, copy2_b, hnew, partC);

  // 6. zcopy (zexp folded in)
  zcopy_kernel<<<dim3((VC + 1023)/1024, B_), 256, 0, stream>>>(partC, sr, zbuf);

  // 7. final softmax + output assembly
  final_softmax2<<<B_, 256, 0, stream>>>(p0, p1, p2, proj_b, zbuf, out0);
}